// Round 7
// baseline (192.507 us; speedup 1.0000x reference)
//
#include <hip/hip_runtime.h>

#define NN 4096
#define DD 512
#define HH 8
#define FF 64
#define LRELU_ALPHA 0.2f
#define SP 72   // LDS row stride in bf16 elems
#define JH 1024 // per-subhalf j-length in k_attn (2 subhalves per block, 2 z-blocks)

typedef __attribute__((ext_vector_type(8))) short bf16x8;
typedef __attribute__((ext_vector_type(4))) float f32x4;

__device__ __forceinline__ float f4c(const float4& v, int k) {
    return k == 0 ? v.x : (k == 1 ? v.y : (k == 2 ? v.z : v.w));
}
__device__ __forceinline__ void f4s(float4& v, int k, float x) {
    if (k == 0) v.x = x; else if (k == 1) v.y = x; else if (k == 2) v.z = x; else v.w = x;
}
__device__ __forceinline__ unsigned short f2bf(float x) {   // RNE float->bf16
    unsigned u = __float_as_uint(x);
    return (unsigned short)((u + 0x7fffu + ((u >> 16) & 1u)) >> 16);
}
__device__ __forceinline__ float bf2f(unsigned short h) {
    return __uint_as_float(((unsigned)h) << 16);
}
// monotone float<->uint key for atomicMax on arbitrary-sign floats
__device__ __forceinline__ unsigned fkey(float x) {
    unsigned u = __float_as_uint(x);
    return (u & 0x80000000u) ? ~u : (u | 0x80000000u);
}
__device__ __forceinline__ float funkey(unsigned k) {
    unsigned u = (k & 0x80000000u) ? (k ^ 0x80000000u) : ~k;
    return __uint_as_float(u);
}

// ================= Kernel 1: fused prep (unchanged from round 6) =================
// [0,2048)     : adjacency -> lane-indexed 64-bit MFMA masks adjm[g][t][16]
// [2048,2112)  : split+transpose W -> wt_hi/wt_lo [h][f][d]
// [2112,2368)  : one-shot hi/lo split of hmat -> h_hi/h_lo [n][d] bf16
// 2368         : zero mxkey + hpsum
__global__ __launch_bounds__(256) void k_prep(const int* __restrict__ adj,
                                              const float* __restrict__ W,
                                              const float* __restrict__ hmat,
                                              unsigned long long* __restrict__ adjm,
                                              unsigned short* __restrict__ wt_hi,
                                              unsigned short* __restrict__ wt_lo,
                                              unsigned short* __restrict__ h_hi,
                                              unsigned short* __restrict__ h_lo,
                                              unsigned* __restrict__ mxkey,
                                              float* __restrict__ hpsum) {
    __shared__ unsigned long long shbuf[2080];   // 16640 B, aliased per branch
    int b = blockIdx.x, t = threadIdx.x;
    if (b < 2048) {
        int g = b >> 3, cs = b & 7;
        int r0 = g * 16;
        int lane = t & 63, wv = t >> 6;
        unsigned long long (*w64)[9] = (unsigned long long(*)[9])shbuf;
        // phase 1: coalesced row-pack of 16 rows x 512 cols into LDS words
        for (int r = 0; r < 16; r++) {
            #pragma unroll
            for (int q = 0; q < 2; q++) {
                int col = cs * 512 + q * 256 + t;
                unsigned long long m = __ballot(adj[(size_t)(r0 + r) * NN + col] > 0);
                if (lane == 0) w64[r][q * 4 + wv] = m;
            }
        }
        __syncthreads();
        // phase 2: transpose-repack into lane-indexed MFMA masks via ballot
        for (int tl = wv; tl < 8; tl += 4) {
            unsigned long long wbits = w64[lane & 15][tl];
            unsigned long long my = 0;
            #pragma unroll
            for (int k = 0; k < 16; k++) {
                int shv = 32 * (k >> 3) + 8 * (lane >> 4) + (k & 7);
                unsigned long long bal = __ballot((unsigned)((wbits >> shv) & 1ULL));
                if (lane == k) my = bal;
            }
            if (lane < 16)
                adjm[((size_t)g * 64 + cs * 8 + tl) * 16 + lane] = my;
        }
    } else if (b < 2112) {
        float (*tile)[65] = (float(*)[65])shbuf;
        int idx = b - 2048;
        int h = idx >> 3;
        int d0 = (idx & 7) * 64;
        #pragma unroll
        for (int kidx = 0; kidx < 4; kidx++) {
            int id = t + 256 * kidx;
            int dd = id >> 4, f4i = (id & 15) * 4;
            float4 v = *(const float4*)(W + ((size_t)(h * DD + d0 + dd)) * FF + f4i);
            tile[dd][f4i] = v.x; tile[dd][f4i + 1] = v.y;
            tile[dd][f4i + 2] = v.z; tile[dd][f4i + 3] = v.w;
        }
        __syncthreads();
        int f = t >> 2, c = (t & 3) * 16;
        union { unsigned short s[16]; uint4 v[2]; } hb, lb;
        #pragma unroll
        for (int q = 0; q < 16; q++) {
            float v = tile[c + q][f];
            unsigned short hi = f2bf(v);
            hb.s[q] = hi;
            lb.s[q] = f2bf(v - bf2f(hi));
        }
        uint4* dh = (uint4*)(wt_hi + ((size_t)h * FF + f) * DD + d0 + c);
        uint4* dl = (uint4*)(wt_lo + ((size_t)h * FF + f) * DD + d0 + c);
        dh[0] = hb.v[0]; dh[1] = hb.v[1];
        dl[0] = lb.v[0]; dl[1] = lb.v[1];
    } else if (b < 2368) {
        // one-shot hi/lo split of hmat (bit-identical to the old in-k_hp split)
        int idx = b - 2112;                  // 0..255, 16 rows each
        int row = idx * 16 + (t >> 4);
        int c0 = (t & 15) * 32;
        const float* src = hmat + (size_t)row * DD + c0;
        #pragma unroll
        for (int half = 0; half < 2; half++) {
            float4 p0 = *(const float4*)(src + half * 16);
            float4 p1 = *(const float4*)(src + half * 16 + 4);
            float4 p2 = *(const float4*)(src + half * 16 + 8);
            float4 p3 = *(const float4*)(src + half * 16 + 12);
            union { unsigned short s[16]; uint4 v[2]; } hb, lb;
            #pragma unroll
            for (int q = 0; q < 16; q++) {
                float v = q < 4 ? f4c(p0, q) : q < 8 ? f4c(p1, q - 4)
                          : q < 12 ? f4c(p2, q - 8) : f4c(p3, q - 12);
                unsigned short hi = f2bf(v);
                hb.s[q] = hi;
                lb.s[q] = f2bf(v - bf2f(hi));
            }
            uint4* dh = (uint4*)(h_hi + (size_t)row * DD + c0 + half * 16);
            uint4* dl = (uint4*)(h_lo + (size_t)row * DD + c0 + half * 16);
            dh[0] = hb.v[0]; dh[1] = hb.v[1];
            dl[0] = lb.v[0]; dl[1] = lb.v[1];
        }
    } else {
        if (t < 16) mxkey[t] = 0u;
        hpsum[t] = 0.f;
        hpsum[t + 256] = 0.f;
    }
}

// ================= Kernel 2: hp GEMM (unchanged from round 6) ========
__global__ __launch_bounds__(256) void k_hp_mfma(const unsigned short* __restrict__ hhi,
                                                 const unsigned short* __restrict__ hlo,
                                                 const unsigned short* __restrict__ whi,
                                                 const unsigned short* __restrict__ wlo,
                                                 const float* __restrict__ a,
                                                 unsigned short* __restrict__ hpT_hi,
                                                 float* __restrict__ fs,
                                                 float* __restrict__ fd,
                                                 float* __restrict__ hpsum,
                                                 unsigned* __restrict__ mxkey) {
    __shared__ char smem[4 * 64 * SP * 2];   // 36864 B
    unsigned short* ah = (unsigned short*)smem;
    unsigned short* al = ah + 64 * SP;
    unsigned short* bh = al + 64 * SP;
    unsigned short* bl = bh + 64 * SP;

    int t = threadIdx.x;
    int h = blockIdx.y;
    int n0 = blockIdx.x * 64;
    int lane = t & 63;
    int w = t >> 6;
    int R0 = (w >> 1) * 32, F0 = (w & 1) * 32;
    int am = lane & 15, aq = lane >> 4;
    int sr = t >> 2, sc = (t & 3) * 16;

    const unsigned short* ghh = hhi + (size_t)(n0 + sr) * DD;
    const unsigned short* ghl = hlo + (size_t)(n0 + sr) * DD;
    const unsigned short* gbh = whi + ((size_t)h * FF + sr) * DD;
    const unsigned short* gbl = wlo + ((size_t)h * FF + sr) * DD;

    f32x4 acc[2][2] = {};
    for (int kk = 0; kk < DD; kk += 64) {
        {   // h: pre-split bf16 hi/lo copies
            const uint4* s0 = (const uint4*)(ghh + kk + sc);
            const uint4* s1 = (const uint4*)(ghl + kk + sc);
            uint4 h0 = s0[0], h1 = s0[1], l0 = s1[0], l1 = s1[1];
            *(uint4*)(ah + sr * SP + sc) = h0; *(uint4*)(ah + sr * SP + sc + 8) = h1;
            *(uint4*)(al + sr * SP + sc) = l0; *(uint4*)(al + sr * SP + sc + 8) = l1;
        }
        {
            const uint4* s2 = (const uint4*)(gbh + kk + sc);
            const uint4* s3 = (const uint4*)(gbl + kk + sc);
            uint4 w0 = s2[0], w1 = s2[1], x0 = s3[0], x1 = s3[1];
            *(uint4*)(bh + sr * SP + sc) = w0; *(uint4*)(bh + sr * SP + sc + 8) = w1;
            *(uint4*)(bl + sr * SP + sc) = x0; *(uint4*)(bl + sr * SP + sc + 8) = x1;
        }
        __syncthreads();
        #pragma unroll
        for (int k2 = 0; k2 < 2; k2++) {
            int ko = k2 * 32 + aq * 8;
            bf16x8 a0h = *(const bf16x8*)(ah + (R0 + am) * SP + ko);
            bf16x8 a1h = *(const bf16x8*)(ah + (R0 + 16 + am) * SP + ko);
            bf16x8 a0l = *(const bf16x8*)(al + (R0 + am) * SP + ko);
            bf16x8 a1l = *(const bf16x8*)(al + (R0 + 16 + am) * SP + ko);
            bf16x8 b0h = *(const bf16x8*)(bh + (F0 + am) * SP + ko);
            bf16x8 b1h = *(const bf16x8*)(bh + (F0 + 16 + am) * SP + ko);
            bf16x8 b0l = *(const bf16x8*)(bl + (F0 + am) * SP + ko);
            bf16x8 b1l = *(const bf16x8*)(bl + (F0 + 16 + am) * SP + ko);
            acc[0][0] = __builtin_amdgcn_mfma_f32_16x16x32_bf16(a0h, b0h, acc[0][0], 0, 0, 0);
            acc[0][1] = __builtin_amdgcn_mfma_f32_16x16x32_bf16(a0h, b1h, acc[0][1], 0, 0, 0);
            acc[1][0] = __builtin_amdgcn_mfma_f32_16x16x32_bf16(a1h, b0h, acc[1][0], 0, 0, 0);
            acc[1][1] = __builtin_amdgcn_mfma_f32_16x16x32_bf16(a1h, b1h, acc[1][1], 0, 0, 0);
            acc[0][0] = __builtin_amdgcn_mfma_f32_16x16x32_bf16(a0h, b0l, acc[0][0], 0, 0, 0);
            acc[0][1] = __builtin_amdgcn_mfma_f32_16x16x32_bf16(a0h, b1l, acc[0][1], 0, 0, 0);
            acc[1][0] = __builtin_amdgcn_mfma_f32_16x16x32_bf16(a1h, b0l, acc[1][0], 0, 0, 0);
            acc[1][1] = __builtin_amdgcn_mfma_f32_16x16x32_bf16(a1h, b1l, acc[1][1], 0, 0, 0);
            acc[0][0] = __builtin_amdgcn_mfma_f32_16x16x32_bf16(a0l, b0h, acc[0][0], 0, 0, 0);
            acc[0][1] = __builtin_amdgcn_mfma_f32_16x16x32_bf16(a0l, b1h, acc[0][1], 0, 0, 0);
            acc[1][0] = __builtin_amdgcn_mfma_f32_16x16x32_bf16(a1l, b0h, acc[1][0], 0, 0, 0);
            acc[1][1] = __builtin_amdgcn_mfma_f32_16x16x32_bf16(a1l, b1h, acc[1][1], 0, 0, 0);
        }
        __syncthreads();
    }

    // Epilogue: pack hi/lo to LDS [f][n], store hi, fs/fd (scaled by LOG2E), maxfd, hpsum.
    unsigned* tt = (unsigned*)smem;
    float* rs = (float*)(smem + 17408);
    float* rd = rs + 256;
    float* ash = rd + 256;
    if (t < 128) ash[t] = a[h * 2 * FF + t];
    int col = lane & 15, rbase = (lane >> 4) * 4;
    #pragma unroll
    for (int m16 = 0; m16 < 2; m16++) {
        #pragma unroll
        for (int n16 = 0; n16 < 2; n16++) {
            #pragma unroll
            for (int r = 0; r < 4; r++) {
                int nl = R0 + m16 * 16 + rbase + r;
                int f = F0 + n16 * 16 + col;
                float v = acc[m16][n16][r];
                unsigned short hi = f2bf(v);
                unsigned short lo = f2bf(v - bf2f(hi));
                tt[f * 68 + nl] = (unsigned)hi | ((unsigned)lo << 16);
            }
        }
    }
    __syncthreads();
    {
        int f = t >> 2, c = (t & 3) * 16;
        union { unsigned short s[16]; uint4 v[2]; } hb;
        float csum = 0.f;
        #pragma unroll
        for (int q = 0; q < 16; q++) {
            unsigned u = tt[f * 68 + c + q];
            hb.s[q] = (unsigned short)(u & 0xffffu);
            csum += bf2f((unsigned short)(u & 0xffffu)) + bf2f((unsigned short)(u >> 16));
        }
        uint4* dh = (uint4*)(hpT_hi + ((size_t)h * FF + f) * NN + n0 + c);
        dh[0] = hb.v[0]; dh[1] = hb.v[1];
        csum += __shfl_xor(csum, 1);
        csum += __shfl_xor(csum, 2);
        if ((t & 3) == 0) unsafeAtomicAdd(hpsum + h * FF + f, csum);
    }
    {
        int n = t & 63, g = t >> 6;
        float fsp = 0.f, fdp = 0.f;
        #pragma unroll
        for (int q = 0; q < 16; q++) {
            int f = g * 16 + q;
            unsigned u = tt[f * 68 + n];
            float v = bf2f((unsigned short)(u & 0xffffu)) + bf2f((unsigned short)(u >> 16));
            fsp += v * ash[f];
            fdp += v * ash[64 + f];
        }
        rs[g * 64 + n] = fsp;
        rd[g * 64 + n] = fdp;
    }
    __syncthreads();
    if (t < 64) {
        const float LOG2E = 1.44269504f;
        float fdv = (rd[t] + rd[64 + t] + rd[128 + t] + rd[192 + t]) * LOG2E;
        fs[(size_t)h * NN + n0 + t] = (rs[t] + rs[64 + t] + rs[128 + t] + rs[192 + t]) * LOG2E;
        fd[(size_t)h * NN + n0 + t] = fdv;
        unsigned key = fkey(fdv);
        #pragma unroll
        for (int off = 32; off; off >>= 1) key = max(key, (unsigned)__shfl_xor((int)key, off));
        if (t == 0) atomicMax(mxkey + h, key);
    }
}

// ================= Kernel 3: attention — round-4 body, z-split partials (no atomics) =======
// grid (NN/64, HH, 2), 512 threads = 8 waves. Block z covers j in [z*2048, z*2048+2048);
// inside: wave w = (subhalf h2 = w>>2 of 1024 cols) x (row-group rg = w&3, 16 rows).
// Identical verified loop body; in-block LDS combine; per-block partial O + rowsum
// written with plain coalesced f32x4 stores (z=0 -> out buffer, z=1 -> poacc).
__global__ __launch_bounds__(512) void k_attn(const float* __restrict__ fs,
                                              const float* __restrict__ fd,
                                              const unsigned* __restrict__ mxkey,
                                              const unsigned long long* __restrict__ adjm,
                                              const unsigned short* __restrict__ hpT_hi,
                                              float* __restrict__ outp,
                                              float* __restrict__ poacc,
                                              float* __restrict__ pli) {
    __shared__ unsigned short hbh[2][2][64 * SP];   // [dbuf][subhalf][f*SP+j] = 36864 B

    int t = threadIdx.x;
    int h = blockIdx.y;
    int i0 = blockIdx.x * 64;
    int z = blockIdx.z;
    int lane = t & 63;
    int w = t >> 6;              // 0..7
    int h2 = w >> 2;             // subhalf within this block's 2048-j range
    int rg = w & 3;              // row-group
    int am = lane & 15, aq = lane >> 4;
    int th = t >> 8;             // staging: which subhalf's tile this thread fills
    int ts = t & 255;
    int sr = ts >> 2, sc = (ts & 3) * 16;

    // per-row constants (scaled domain): arg = max(tv, 0.2*tv + Ci), tv = Ai + fdL_j
    float mfdL = funkey(mxkey[h]);
    float fsv = fs[(size_t)h * NN + i0 + rg * 16 + am];
    float sL = fsv + mfdL;
    float mrL = fmaxf(sL, LRELU_ALPHA * sL);
    float Ai = fsv - mrL;
    float Ci = -0.8f * mrL;

    int rgu = __builtin_amdgcn_readfirstlane(rg);
    int h2u = __builtin_amdgcn_readfirstlane(h2);
    const unsigned long long* mbase = adjm + ((size_t)(blockIdx.x * 4 + rgu) * 64) * 16;
    const unsigned short* gH = hpT_hi + (size_t)h * FF * NN;
    const float* fdh = fd + (size_t)h * NN + (size_t)z * 2048 + (size_t)h2u * JH;

    f32x4 acc[4] = {};
    f32x4 accl = {};
    bf16x8 ones;
    #pragma unroll
    for (int i = 0; i < 8; i++) ones[i] = (short)0x3f80;   // bf16 1.0

    auto stage_load = [&](int j0, uint4& v0, uint4& v1) {   // j0 relative to subhalf
        const uint4* s = (const uint4*)(gH + (size_t)sr * NN + z * 2048 + th * JH + j0 + sc);
        v0 = s[0]; v1 = s[1];
    };
    auto stage_write = [&](int buf, uint4 v0, uint4 v1) {
        *(uint4*)(&hbh[buf][th][sr * SP + sc]) = v0;
        *(uint4*)(&hbh[buf][th][sr * SP + sc + 8]) = v1;
    };
    auto fd_load = [&](int j0, float4* p) {
        p[0] = *(const float4*)(fdh + j0 + aq * 8);
        p[1] = *(const float4*)(fdh + j0 + aq * 8 + 4);
        p[2] = *(const float4*)(fdh + j0 + 32 + aq * 8);
        p[3] = *(const float4*)(fdh + j0 + 32 + aq * 8 + 4);
    };
    // 8 scores -> one bf16x8 B-fragment; masks are wave-uniform 64-bit lane masks
    auto mkfrag = [&](float4 p0, float4 p1, const unsigned long long* mk, int off) -> bf16x8 {
        unsigned eu[8];
        #pragma unroll
        for (int q = 0; q < 2; q++) {
            float4 pv = q ? p1 : p0;
            #pragma unroll
            for (int bq = 0; bq < 4; bq++) {
                float tv = Ai + f4c(pv, bq);
                float uv = __builtin_fmaf(LRELU_ALPHA, tv, Ci);
                float ev = __builtin_amdgcn_exp2f(fmaxf(tv, uv));
                unsigned r;
                asm("v_cndmask_b32 %0, 0, %1, %2"
                    : "=v"(r) : "v"(ev), "s"(mk[off + q * 4 + bq]));
                eu[q * 4 + bq] = r;
            }
        }
        union { unsigned u[4]; bf16x8 v; } pk;
        pk.u[0] = __builtin_amdgcn_perm(eu[1], eu[0], 0x07060302);
        pk.u[1] = __builtin_amdgcn_perm(eu[3], eu[2], 0x07060302);
        pk.u[2] = __builtin_amdgcn_perm(eu[5], eu[4], 0x07060302);
        pk.u[3] = __builtin_amdgcn_perm(eu[7], eu[6], 0x07060302);
        return pk.v;
    };

    bf16x8 Pc0, Pc1;
    {   // prologue: tile 0 of each subhalf
        uint4 v0, v1; float4 pf[4];
        stage_load(0, v0, v1);
        fd_load(0, pf);
        unsigned long long mk[16];
        size_t jt = (size_t)(z * 32 + h2u * 16) * 16;
        #pragma unroll
        for (int k = 0; k < 16; k++) mk[k] = mbase[jt + k];
        Pc0 = mkfrag(pf[0], pf[1], mk, 0);
        Pc1 = mkfrag(pf[2], pf[3], mk, 8);
        stage_write(0, v0, v1);
        __syncthreads();
    }

    for (int j0 = 0; j0 < JH; j0 += 64) {
        int cur = (j0 >> 6) & 1;
        int jn = (j0 + 64) & (JH - 1);   // wraps on last iter; produce is harmless then
        uint4 v0, v1; float4 pf[4];
        stage_load(jn, v0, v1);          // issue next-tile loads early (T14)
        fd_load(jn, pf);
        unsigned long long mk[16];
        size_t jt = (size_t)(z * 32 + h2u * 16 + (jn >> 6)) * 16;
        #pragma unroll
        for (int k = 0; k < 16; k++) mk[k] = mbase[jt + k];

        // consume current tile of this wave's subhalf: hp A-frags from LDS, P from registers
        #pragma unroll
        for (int k2 = 0; k2 < 2; k2++) {
            int ko = k2 * 32 + aq * 8;
            bf16x8 x0 = *(const bf16x8*)(&hbh[cur][h2][(am)      * SP + ko]);
            bf16x8 x1 = *(const bf16x8*)(&hbh[cur][h2][(am + 16) * SP + ko]);
            bf16x8 x2 = *(const bf16x8*)(&hbh[cur][h2][(am + 32) * SP + ko]);
            bf16x8 x3 = *(const bf16x8*)(&hbh[cur][h2][(am + 48) * SP + ko]);
            bf16x8 P = k2 ? Pc1 : Pc0;
            acc[0] = __builtin_amdgcn_mfma_f32_16x16x32_bf16(x0, P, acc[0], 0, 0, 0);
            acc[1] = __builtin_amdgcn_mfma_f32_16x16x32_bf16(x1, P, acc[1], 0, 0, 0);
            acc[2] = __builtin_amdgcn_mfma_f32_16x16x32_bf16(x2, P, acc[2], 0, 0, 0);
            acc[3] = __builtin_amdgcn_mfma_f32_16x16x32_bf16(x3, P, acc[3], 0, 0, 0);
            accl   = __builtin_amdgcn_mfma_f32_16x16x32_bf16(ones, P, accl, 0, 0, 0);
        }

        stage_write(cur ^ 1, v0, v1);    // write next hp tile (other buffer)
        Pc0 = mkfrag(pf[0], pf[1], mk, 0);
        Pc1 = mkfrag(pf[2], pf[3], mk, 8);
        __syncthreads();
    }

    // Cross-subhalf combine in LDS, then write this z-block's PARTIAL (coalesced, no atomics).
    float* cb = (float*)hbh;                 // 4096 + 256 floats = 17.4 KB
    if (h2 == 1) {
        #pragma unroll
        for (int mf = 0; mf < 4; mf++)
            *(f32x4*)&cb[((rg * 4 + mf) * 64 + lane) * 4] = acc[mf];
        cb[4096 + rg * 64 + lane] = accl[0];
    }
    __syncthreads();
    if (h2 == 0) {
        #pragma unroll
        for (int mf = 0; mf < 4; mf++) {
            f32x4 o = *(const f32x4*)&cb[((rg * 4 + mf) * 64 + lane) * 4];
            acc[mf] += o;
        }
        float li = accl[0] + cb[4096 + rg * 64 + lane];
        int row = i0 + rg * 16 + am;
        float* dst = (z == 0) ? outp : poacc;           // same [row][h][f] layout
        float* drow = dst + (size_t)row * (HH * FF) + h * FF;
        #pragma unroll
        for (int mf = 0; mf < 4; mf++)
            *(f32x4*)(drow + mf * 16 + aq * 4) = acc[mf];
        if (aq == 0) pli[(size_t)z * NN * HH + (size_t)row * HH + h] = li;
    }
}

// ================= Kernel 4: combine — sum 2 partials, normalize + fallback + ELU ==========
__global__ __launch_bounds__(256) void k_comb(float* __restrict__ outp,
                                              const float* __restrict__ poacc,
                                              const float* __restrict__ pli,
                                              const float* __restrict__ hpsum) {
    int gid = blockIdx.x * 256 + threadIdx.x;          // one float4 of the output
    const float invN = 1.0f / NN;
    float4 v0 = ((const float4*)outp)[gid];
    float4 v1 = ((const float4*)poacc)[gid];
    int rh = gid >> 4;                                  // row*HH + h
    int h = rh & (HH - 1);
    int f0 = (gid & 15) * 4;
    float li = pli[rh] + pli[NN * HH + rh];
    float4 o;
    if (li > 0.f) {
        float rl = 1.f / li;
        o.x = (v0.x + v1.x) * rl; o.y = (v0.y + v1.y) * rl;
        o.z = (v0.z + v1.z) * rl; o.w = (v0.w + v1.w) * rl;
    } else {                                            // all-masked row fallback
        o.x = hpsum[h * FF + f0]     * invN; o.y = hpsum[h * FF + f0 + 1] * invN;
        o.z = hpsum[h * FF + f0 + 2] * invN; o.w = hpsum[h * FF + f0 + 3] * invN;
    }
    o.x = o.x > 0.f ? o.x : __expf(o.x) - 1.f;
    o.y = o.y > 0.f ? o.y : __expf(o.y) - 1.f;
    o.z = o.z > 0.f ? o.z : __expf(o.z) - 1.f;
    o.w = o.w > 0.f ? o.w : __expf(o.w) - 1.f;
    ((float4*)outp)[gid] = o;
}

extern "C" void kernel_launch(void* const* d_in, const int* in_sizes, int n_in,
                              void* d_out, int out_size, void* d_ws, size_t ws_size,
                              hipStream_t stream) {
    const float* hmat = (const float*)d_in[0];
    const int*   adj  = (const int*)d_in[1];
    const float* W    = (const float*)d_in[2];
    const float* a    = (const float*)d_in[3];
    float* out = (float*)d_out;

    char* ws = (char*)d_ws;
    unsigned short* hpT_hi = (unsigned short*)(ws);                 // 4 MB
    unsigned long long* adjm = (unsigned long long*)(ws + (4u << 20)); // 2 MB
    unsigned short* wt_hi  = (unsigned short*)(ws + (6u << 20));    // 512 KB
    unsigned short* wt_lo  = (unsigned short*)(ws + (6u << 20) + (512u << 10));
    float* fs    = (float*)(ws + (7u << 20));                       // 128 KB
    float* fd    = (float*)(ws + (7u << 20) + (128u << 10));        // 128 KB
    unsigned* mxkey = (unsigned*)(ws + (7u << 20) + (256u << 10));  // 64 B
    float* hpsum = (float*)(mxkey + 16);                            // 2 KB
    float* pli   = (float*)(ws + (7u << 20) + (384u << 10));        // 256 KB [z][row*HH+h]
    unsigned short* h_hi = (unsigned short*)(ws + (8u << 20));      // 4 MB (dead after k_hp)
    unsigned short* h_lo = (unsigned short*)(ws + (12u << 20));     // 4 MB (dead after k_hp)
    float* poacc = (float*)(ws + (8u << 20));                       // 8 MB, aliases h_hi/h_lo

    k_prep   <<<dim3(2369),            256, 0, stream>>>(adj, W, hmat, adjm, wt_hi, wt_lo,
                                                         h_hi, h_lo, mxkey, hpsum);
    k_hp_mfma<<<dim3(64, 8),           256, 0, stream>>>(h_hi, h_lo, wt_hi, wt_lo, a,
                                                         hpT_hi, fs, fd, hpsum, mxkey);
    k_attn   <<<dim3(NN / 64, HH, 2),  512, 0, stream>>>(fs, fd, mxkey, adjm,
                                                         hpT_hi, out, poacc, pli);
    k_comb   <<<dim3(NN * HH * FF / 1024), 256, 0, stream>>>(out, poacc, pli, hpsum);
}

// Round 8
// 191.694 us; speedup vs baseline: 1.0042x; 1.0042x over previous
//
#include <hip/hip_runtime.h>

#define NN 4096
#define DD 512
#define HH 8
#define FF 64
#define LRELU_ALPHA 0.2f
#define SP 72   // LDS row stride in bf16 elems
#define JCHUNK 2048   // per-wave j-range (2 subhalves x 1024 handled as 2048/wave-half)

typedef __attribute__((ext_vector_type(8))) short bf16x8;
typedef __attribute__((ext_vector_type(4))) float f32x4;

__device__ __forceinline__ float f4c(const float4& v, int k) {
    return k == 0 ? v.x : (k == 1 ? v.y : (k == 2 ? v.z : v.w));
}
__device__ __forceinline__ void f4s(float4& v, int k, float x) {
    if (k == 0) v.x = x; else if (k == 1) v.y = x; else if (k == 2) v.z = x; else v.w = x;
}
__device__ __forceinline__ unsigned short f2bf(float x) {   // RNE float->bf16
    unsigned u = __float_as_uint(x);
    return (unsigned short)((u + 0x7fffu + ((u >> 16) & 1u)) >> 16);
}
__device__ __forceinline__ float bf2f(unsigned short h) {
    return __uint_as_float(((unsigned)h) << 16);
}
// monotone float<->uint key for atomicMax on arbitrary-sign floats
__device__ __forceinline__ unsigned fkey(float x) {
    unsigned u = __float_as_uint(x);
    return (u & 0x80000000u) ? ~u : (u | 0x80000000u);
}
__device__ __forceinline__ float funkey(unsigned k) {
    unsigned u = (k & 0x80000000u) ? (k ^ 0x80000000u) : ~k;
    return __uint_as_float(u);
}

// ================= Kernel 1: fused prep (unchanged from round 6) =================
// [0,2048)     : adjacency -> lane-indexed 64-bit MFMA masks adjm[g][t][16]
// [2048,2112)  : split+transpose W -> wt_hi/wt_lo [h][f][d]
// [2112,2368)  : one-shot hi/lo split of hmat -> h_hi/h_lo [n][d] bf16
// 2368         : zero mxkey + hpsum
__global__ __launch_bounds__(256) void k_prep(const int* __restrict__ adj,
                                              const float* __restrict__ W,
                                              const float* __restrict__ hmat,
                                              unsigned long long* __restrict__ adjm,
                                              unsigned short* __restrict__ wt_hi,
                                              unsigned short* __restrict__ wt_lo,
                                              unsigned short* __restrict__ h_hi,
                                              unsigned short* __restrict__ h_lo,
                                              unsigned* __restrict__ mxkey,
                                              float* __restrict__ hpsum) {
    __shared__ unsigned long long shbuf[2080];   // 16640 B, aliased per branch
    int b = blockIdx.x, t = threadIdx.x;
    if (b < 2048) {
        int g = b >> 3, cs = b & 7;
        int r0 = g * 16;
        int lane = t & 63, wv = t >> 6;
        unsigned long long (*w64)[9] = (unsigned long long(*)[9])shbuf;
        // phase 1: coalesced row-pack of 16 rows x 512 cols into LDS words
        for (int r = 0; r < 16; r++) {
            #pragma unroll
            for (int q = 0; q < 2; q++) {
                int col = cs * 512 + q * 256 + t;
                unsigned long long m = __ballot(adj[(size_t)(r0 + r) * NN + col] > 0);
                if (lane == 0) w64[r][q * 4 + wv] = m;
            }
        }
        __syncthreads();
        // phase 2: transpose-repack into lane-indexed MFMA masks via ballot
        for (int tl = wv; tl < 8; tl += 4) {
            unsigned long long wbits = w64[lane & 15][tl];
            unsigned long long my = 0;
            #pragma unroll
            for (int k = 0; k < 16; k++) {
                int shv = 32 * (k >> 3) + 8 * (lane >> 4) + (k & 7);
                unsigned long long bal = __ballot((unsigned)((wbits >> shv) & 1ULL));
                if (lane == k) my = bal;
            }
            if (lane < 16)
                adjm[((size_t)g * 64 + cs * 8 + tl) * 16 + lane] = my;
        }
    } else if (b < 2112) {
        float (*tile)[65] = (float(*)[65])shbuf;
        int idx = b - 2048;
        int h = idx >> 3;
        int d0 = (idx & 7) * 64;
        #pragma unroll
        for (int kidx = 0; kidx < 4; kidx++) {
            int id = t + 256 * kidx;
            int dd = id >> 4, f4i = (id & 15) * 4;
            float4 v = *(const float4*)(W + ((size_t)(h * DD + d0 + dd)) * FF + f4i);
            tile[dd][f4i] = v.x; tile[dd][f4i + 1] = v.y;
            tile[dd][f4i + 2] = v.z; tile[dd][f4i + 3] = v.w;
        }
        __syncthreads();
        int f = t >> 2, c = (t & 3) * 16;
        union { unsigned short s[16]; uint4 v[2]; } hb, lb;
        #pragma unroll
        for (int q = 0; q < 16; q++) {
            float v = tile[c + q][f];
            unsigned short hi = f2bf(v);
            hb.s[q] = hi;
            lb.s[q] = f2bf(v - bf2f(hi));
        }
        uint4* dh = (uint4*)(wt_hi + ((size_t)h * FF + f) * DD + d0 + c);
        uint4* dl = (uint4*)(wt_lo + ((size_t)h * FF + f) * DD + d0 + c);
        dh[0] = hb.v[0]; dh[1] = hb.v[1];
        dl[0] = lb.v[0]; dl[1] = lb.v[1];
    } else if (b < 2368) {
        // one-shot hi/lo split of hmat (bit-identical to the old in-k_hp split)
        int idx = b - 2112;                  // 0..255, 16 rows each
        int row = idx * 16 + (t >> 4);
        int c0 = (t & 15) * 32;
        const float* src = hmat + (size_t)row * DD + c0;
        #pragma unroll
        for (int half = 0; half < 2; half++) {
            float4 p0 = *(const float4*)(src + half * 16);
            float4 p1 = *(const float4*)(src + half * 16 + 4);
            float4 p2 = *(const float4*)(src + half * 16 + 8);
            float4 p3 = *(const float4*)(src + half * 16 + 12);
            union { unsigned short s[16]; uint4 v[2]; } hb, lb;
            #pragma unroll
            for (int q = 0; q < 16; q++) {
                float v = q < 4 ? f4c(p0, q) : q < 8 ? f4c(p1, q - 4)
                          : q < 12 ? f4c(p2, q - 8) : f4c(p3, q - 12);
                unsigned short hi = f2bf(v);
                hb.s[q] = hi;
                lb.s[q] = f2bf(v - bf2f(hi));
            }
            uint4* dh = (uint4*)(h_hi + (size_t)row * DD + c0 + half * 16);
            uint4* dl = (uint4*)(h_lo + (size_t)row * DD + c0 + half * 16);
            dh[0] = hb.v[0]; dh[1] = hb.v[1];
            dl[0] = lb.v[0]; dl[1] = lb.v[1];
        }
    } else {
        if (t < 16) mxkey[t] = 0u;
        hpsum[t] = 0.f;
        hpsum[t + 256] = 0.f;
    }
}

// ================= Kernel 2: hp GEMM =================
// Same as round 6 except the t<64 epilogue: instead of fd, store Ej = exp2(fdL) and
// Fj = exp2(alpha*fdL) (max-independent exp factors; per-row max folds into EA/EC in k_attn).
__global__ __launch_bounds__(256) void k_hp_mfma(const unsigned short* __restrict__ hhi,
                                                 const unsigned short* __restrict__ hlo,
                                                 const unsigned short* __restrict__ whi,
                                                 const unsigned short* __restrict__ wlo,
                                                 const float* __restrict__ a,
                                                 unsigned short* __restrict__ hpT_hi,
                                                 float* __restrict__ fs,
                                                 float* __restrict__ ejs,
                                                 float* __restrict__ fjs,
                                                 float* __restrict__ hpsum,
                                                 unsigned* __restrict__ mxkey) {
    __shared__ char smem[4 * 64 * SP * 2];   // 36864 B
    unsigned short* ah = (unsigned short*)smem;
    unsigned short* al = ah + 64 * SP;
    unsigned short* bh = al + 64 * SP;
    unsigned short* bl = bh + 64 * SP;

    int t = threadIdx.x;
    int h = blockIdx.y;
    int n0 = blockIdx.x * 64;
    int lane = t & 63;
    int w = t >> 6;
    int R0 = (w >> 1) * 32, F0 = (w & 1) * 32;
    int am = lane & 15, aq = lane >> 4;
    int sr = t >> 2, sc = (t & 3) * 16;

    const unsigned short* ghh = hhi + (size_t)(n0 + sr) * DD;
    const unsigned short* ghl = hlo + (size_t)(n0 + sr) * DD;
    const unsigned short* gbh = whi + ((size_t)h * FF + sr) * DD;
    const unsigned short* gbl = wlo + ((size_t)h * FF + sr) * DD;

    f32x4 acc[2][2] = {};
    for (int kk = 0; kk < DD; kk += 64) {
        {   // h: pre-split bf16 hi/lo copies
            const uint4* s0 = (const uint4*)(ghh + kk + sc);
            const uint4* s1 = (const uint4*)(ghl + kk + sc);
            uint4 h0 = s0[0], h1 = s0[1], l0 = s1[0], l1 = s1[1];
            *(uint4*)(ah + sr * SP + sc) = h0; *(uint4*)(ah + sr * SP + sc + 8) = h1;
            *(uint4*)(al + sr * SP + sc) = l0; *(uint4*)(al + sr * SP + sc + 8) = l1;
        }
        {
            const uint4* s2 = (const uint4*)(gbh + kk + sc);
            const uint4* s3 = (const uint4*)(gbl + kk + sc);
            uint4 w0 = s2[0], w1 = s2[1], x0 = s3[0], x1 = s3[1];
            *(uint4*)(bh + sr * SP + sc) = w0; *(uint4*)(bh + sr * SP + sc + 8) = w1;
            *(uint4*)(bl + sr * SP + sc) = x0; *(uint4*)(bl + sr * SP + sc + 8) = x1;
        }
        __syncthreads();
        #pragma unroll
        for (int k2 = 0; k2 < 2; k2++) {
            int ko = k2 * 32 + aq * 8;
            bf16x8 a0h = *(const bf16x8*)(ah + (R0 + am) * SP + ko);
            bf16x8 a1h = *(const bf16x8*)(ah + (R0 + 16 + am) * SP + ko);
            bf16x8 a0l = *(const bf16x8*)(al + (R0 + am) * SP + ko);
            bf16x8 a1l = *(const bf16x8*)(al + (R0 + 16 + am) * SP + ko);
            bf16x8 b0h = *(const bf16x8*)(bh + (F0 + am) * SP + ko);
            bf16x8 b1h = *(const bf16x8*)(bh + (F0 + 16 + am) * SP + ko);
            bf16x8 b0l = *(const bf16x8*)(bl + (F0 + am) * SP + ko);
            bf16x8 b1l = *(const bf16x8*)(bl + (F0 + 16 + am) * SP + ko);
            acc[0][0] = __builtin_amdgcn_mfma_f32_16x16x32_bf16(a0h, b0h, acc[0][0], 0, 0, 0);
            acc[0][1] = __builtin_amdgcn_mfma_f32_16x16x32_bf16(a0h, b1h, acc[0][1], 0, 0, 0);
            acc[1][0] = __builtin_amdgcn_mfma_f32_16x16x32_bf16(a1h, b0h, acc[1][0], 0, 0, 0);
            acc[1][1] = __builtin_amdgcn_mfma_f32_16x16x32_bf16(a1h, b1h, acc[1][1], 0, 0, 0);
            acc[0][0] = __builtin_amdgcn_mfma_f32_16x16x32_bf16(a0h, b0l, acc[0][0], 0, 0, 0);
            acc[0][1] = __builtin_amdgcn_mfma_f32_16x16x32_bf16(a0h, b1l, acc[0][1], 0, 0, 0);
            acc[1][0] = __builtin_amdgcn_mfma_f32_16x16x32_bf16(a1h, b0l, acc[1][0], 0, 0, 0);
            acc[1][1] = __builtin_amdgcn_mfma_f32_16x16x32_bf16(a1h, b1l, acc[1][1], 0, 0, 0);
            acc[0][0] = __builtin_amdgcn_mfma_f32_16x16x32_bf16(a0l, b0h, acc[0][0], 0, 0, 0);
            acc[0][1] = __builtin_amdgcn_mfma_f32_16x16x32_bf16(a0l, b1h, acc[0][1], 0, 0, 0);
            acc[1][0] = __builtin_amdgcn_mfma_f32_16x16x32_bf16(a1l, b0h, acc[1][0], 0, 0, 0);
            acc[1][1] = __builtin_amdgcn_mfma_f32_16x16x32_bf16(a1l, b1h, acc[1][1], 0, 0, 0);
        }
        __syncthreads();
    }

    // Epilogue: pack hi/lo to LDS [f][n], store hi, fs (scaled), Ej/Fj, maxfd, hpsum.
    unsigned* tt = (unsigned*)smem;
    float* rs = (float*)(smem + 17408);
    float* rd = rs + 256;
    float* ash = rd + 256;
    if (t < 128) ash[t] = a[h * 2 * FF + t];
    int col = lane & 15, rbase = (lane >> 4) * 4;
    #pragma unroll
    for (int m16 = 0; m16 < 2; m16++) {
        #pragma unroll
        for (int n16 = 0; n16 < 2; n16++) {
            #pragma unroll
            for (int r = 0; r < 4; r++) {
                int nl = R0 + m16 * 16 + rbase + r;
                int f = F0 + n16 * 16 + col;
                float v = acc[m16][n16][r];
                unsigned short hi = f2bf(v);
                unsigned short lo = f2bf(v - bf2f(hi));
                tt[f * 68 + nl] = (unsigned)hi | ((unsigned)lo << 16);
            }
        }
    }
    __syncthreads();
    {
        int f = t >> 2, c = (t & 3) * 16;
        union { unsigned short s[16]; uint4 v[2]; } hb;
        float csum = 0.f;
        #pragma unroll
        for (int q = 0; q < 16; q++) {
            unsigned u = tt[f * 68 + c + q];
            hb.s[q] = (unsigned short)(u & 0xffffu);
            csum += bf2f((unsigned short)(u & 0xffffu)) + bf2f((unsigned short)(u >> 16));
        }
        uint4* dh = (uint4*)(hpT_hi + ((size_t)h * FF + f) * NN + n0 + c);
        dh[0] = hb.v[0]; dh[1] = hb.v[1];
        csum += __shfl_xor(csum, 1);
        csum += __shfl_xor(csum, 2);
        if ((t & 3) == 0) unsafeAtomicAdd(hpsum + h * FF + f, csum);
    }
    {
        int n = t & 63, g = t >> 6;
        float fsp = 0.f, fdp = 0.f;
        #pragma unroll
        for (int q = 0; q < 16; q++) {
            int f = g * 16 + q;
            unsigned u = tt[f * 68 + n];
            float v = bf2f((unsigned short)(u & 0xffffu)) + bf2f((unsigned short)(u >> 16));
            fsp += v * ash[f];
            fdp += v * ash[64 + f];
        }
        rs[g * 64 + n] = fsp;
        rd[g * 64 + n] = fdp;
    }
    __syncthreads();
    if (t < 64) {
        const float LOG2E = 1.44269504f;
        float fdv = (rd[t] + rd[64 + t] + rd[128 + t] + rd[192 + t]) * LOG2E;
        fs[(size_t)h * NN + n0 + t] = (rs[t] + rs[64 + t] + rs[128 + t] + rs[192 + t]) * LOG2E;
        ejs[(size_t)h * NN + n0 + t] = __builtin_amdgcn_exp2f(fdv);
        fjs[(size_t)h * NN + n0 + t] = __builtin_amdgcn_exp2f(LRELU_ALPHA * fdv);
        unsigned key = fkey(fdv);
        #pragma unroll
        for (int off = 32; off; off >>= 1) key = max(key, (unsigned)__shfl_xor((int)key, off));
        if (t == 0) atomicMax(mxkey + h, key);
    }
}

// ================= Kernel 3: attention — round-6 structure, exp-free scores, ================
// =================            mkfrag pipelined one iteration ahead          ================
// grid (NN/64, HH), 512 threads = 8 waves. Wave w: j-half h2 = w>>2 (2048 cols),
// row-group rg = w&3 (16 i-rows). One barrier per 64-j iteration; LDS combine epilogue.
// Score: e = max(EA*Ej, EC*Fj) (exp2 monotone => equals exp2(leakyrelu) / exp2(max)).
// P fragments for tile k+1 are built at iter k from ej/fj/mask data issued at iter k-1
// (fully landed -> no load-wait in mkfrag). Loop unrolled x2 for static register sets.
__global__ __launch_bounds__(512) void k_attn(const float* __restrict__ fs,
                                              const float* __restrict__ ejs,
                                              const float* __restrict__ fjs,
                                              const unsigned* __restrict__ mxkey,
                                              const unsigned long long* __restrict__ adjm,
                                              const unsigned short* __restrict__ hpT_hi,
                                              const float* __restrict__ hpsum,
                                              float* __restrict__ outp) {
    __shared__ unsigned short hbh[2][2][64 * SP];   // [dbuf][j-half][f*SP+j] = 36864 B

    int t = threadIdx.x;
    int h = blockIdx.y;
    int i0 = blockIdx.x * 64;
    int lane = t & 63;
    int w = t >> 6;              // 0..7
    int h2 = w >> 2;             // j-half
    int rg = w & 3;              // row-group
    int am = lane & 15, aq = lane >> 4;
    int th = t >> 8;             // staging: which half's tile this thread fills
    int ts = t & 255;
    int sr = ts >> 2, sc = (ts & 3) * 16;

    // per-row exp factors: e_pos = EA*Ej, e_neg = EC*Fj  (scaled/log2 domain throughout)
    float mfdL = funkey(mxkey[h]);
    float fsv = fs[(size_t)h * NN + i0 + rg * 16 + am];
    float sL = fsv + mfdL;
    float mrL = fmaxf(sL, LRELU_ALPHA * sL);
    float EA = __builtin_amdgcn_exp2f(fsv - mrL);
    float EC = __builtin_amdgcn_exp2f(LRELU_ALPHA * fsv - mrL);

    int rgu = __builtin_amdgcn_readfirstlane(rg);
    int h2u = __builtin_amdgcn_readfirstlane(h2);
    const unsigned long long* mbase = adjm + ((size_t)(blockIdx.x * 4 + rgu) * 64) * 16;
    const unsigned short* gH = hpT_hi + (size_t)h * FF * NN;
    const float* ejh = ejs + (size_t)h * NN + (size_t)h2u * JCHUNK;
    const float* fjh = fjs + (size_t)h * NN + (size_t)h2u * JCHUNK;

    f32x4 acc[4] = {};
    f32x4 accl = {};
    bf16x8 ones;
    #pragma unroll
    for (int i = 0; i < 8; i++) ones[i] = (short)0x3f80;   // bf16 1.0

    auto stage_load = [&](int j0, uint4& v0, uint4& v1) {   // j0 relative to half
        const uint4* s = (const uint4*)(gH + (size_t)sr * NN + th * JCHUNK + j0 + sc);
        v0 = s[0]; v1 = s[1];
    };
    auto stage_write = [&](int buf, uint4 v0, uint4 v1) {
        *(uint4*)(&hbh[buf][th][sr * SP + sc]) = v0;
        *(uint4*)(&hbh[buf][th][sr * SP + sc + 8]) = v1;
    };
    auto ejf_load = [&](int j0, float4* pe, float4* pf) {
        pe[0] = *(const float4*)(ejh + j0 + aq * 8);
        pe[1] = *(const float4*)(ejh + j0 + aq * 8 + 4);
        pe[2] = *(const float4*)(ejh + j0 + 32 + aq * 8);
        pe[3] = *(const float4*)(ejh + j0 + 32 + aq * 8 + 4);
        pf[0] = *(const float4*)(fjh + j0 + aq * 8);
        pf[1] = *(const float4*)(fjh + j0 + aq * 8 + 4);
        pf[2] = *(const float4*)(fjh + j0 + 32 + aq * 8);
        pf[3] = *(const float4*)(fjh + j0 + 32 + aq * 8 + 4);
    };
    // 8 scores -> one bf16x8 B-fragment; masks are wave-uniform 64-bit lane masks
    auto mkfrag = [&](const float4* pe, const float4* pf,
                      const unsigned long long* mk, int off) -> bf16x8 {
        unsigned eu[8];
        #pragma unroll
        for (int q = 0; q < 2; q++) {
            float4 ev4 = pe[q], fv4 = pf[q];
            #pragma unroll
            for (int bq = 0; bq < 4; bq++) {
                float e = fmaxf(EA * f4c(ev4, bq), EC * f4c(fv4, bq));
                unsigned r;
                asm("v_cndmask_b32 %0, 0, %1, %2"
                    : "=v"(r) : "v"(e), "s"(mk[off + q * 4 + bq]));
                eu[q * 4 + bq] = r;
            }
        }
        union { unsigned u[4]; bf16x8 v; } pk;
        pk.u[0] = __builtin_amdgcn_perm(eu[1], eu[0], 0x07060302);
        pk.u[1] = __builtin_amdgcn_perm(eu[3], eu[2], 0x07060302);
        pk.u[2] = __builtin_amdgcn_perm(eu[5], eu[4], 0x07060302);
        pk.u[3] = __builtin_amdgcn_perm(eu[7], eu[6], 0x07060302);
        return pk.v;
    };
    auto consume = [&](int cur, bf16x8 P0, bf16x8 P1) {
        #pragma unroll
        for (int k2 = 0; k2 < 2; k2++) {
            int ko = k2 * 32 + aq * 8;
            bf16x8 x0 = *(const bf16x8*)(&hbh[cur][h2][(am)      * SP + ko]);
            bf16x8 x1 = *(const bf16x8*)(&hbh[cur][h2][(am + 16) * SP + ko]);
            bf16x8 x2 = *(const bf16x8*)(&hbh[cur][h2][(am + 32) * SP + ko]);
            bf16x8 x3 = *(const bf16x8*)(&hbh[cur][h2][(am + 48) * SP + ko]);
            bf16x8 P = k2 ? P1 : P0;
            acc[0] = __builtin_amdgcn_mfma_f32_16x16x32_bf16(x0, P, acc[0], 0, 0, 0);
            acc[1] = __builtin_amdgcn_mfma_f32_16x16x32_bf16(x1, P, acc[1], 0, 0, 0);
            acc[2] = __builtin_amdgcn_mfma_f32_16x16x32_bf16(x2, P, acc[2], 0, 0, 0);
            acc[3] = __builtin_amdgcn_mfma_f32_16x16x32_bf16(x3, P, acc[3], 0, 0, 0);
            accl   = __builtin_amdgcn_mfma_f32_16x16x32_bf16(ones, P, accl, 0, 0, 0);
        }
    };

    // ---- pipelined state ----
    bf16x8 Pc0, Pc1;                     // P for the tile being consumed
    uint4 svA0, svA1, svB0, svB1;        // staged hp regs (next tile to write)
    float4 peA[4], pfA[4], peB[4], pfB[4];
    unsigned long long mkA[16], mkB[16];

    {   // prologue: tile 0 (P + LDS) and tile 1 (pending regs)
        uint4 v0, v1; float4 pe0[4], pf0[4];
        unsigned long long mk0[16];
        stage_load(0, v0, v1);
        ejf_load(0, pe0, pf0);
        #pragma unroll
        for (int k = 0; k < 16; k++) mk0[k] = mbase[(size_t)(h2u * 32) * 16 + k];
        Pc0 = mkfrag(pe0, pf0, mk0, 0);
        Pc1 = mkfrag(pe0 + 2, pf0 + 2, mk0, 8);
        stage_write(0, v0, v1);
        stage_load(64, svA0, svA1);              // tile 1 stage data
        ejf_load(64, peA, pfA);                  // tile 1 score data
        #pragma unroll
        for (int k = 0; k < 16; k++) mkA[k] = mbase[(size_t)(h2u * 32 + 1) * 16 + k];
        __syncthreads();
    }

    for (int j0 = 0; j0 < JCHUNK; j0 += 128) {
        {   // even iter k: consume buf0 (tile k); write tile k+1; issue tile k+2 into B
            stage_write(1, svA0, svA1);
            int j2 = (j0 + 128) & (JCHUNK - 1);
            stage_load(j2, svB0, svB1);
            ejf_load(j2, peB, pfB);
            #pragma unroll
            for (int k = 0; k < 16; k++)
                mkB[k] = mbase[(size_t)(h2u * 32 + (j2 >> 6)) * 16 + k];
            consume(0, Pc0, Pc1);
            Pc0 = mkfrag(peA, pfA, mkA, 0);      // P for tile k+1 (data from iter k-1)
            Pc1 = mkfrag(peA + 2, pfA + 2, mkA, 8);
            __syncthreads();
        }
        {   // odd iter k+1: consume buf1 (tile k+1); write tile k+2; issue tile k+3 into A
            stage_write(0, svB0, svB1);
            int j3 = (j0 + 192) & (JCHUNK - 1);
            stage_load(j3, svA0, svA1);
            ejf_load(j3, peA, pfA);
            #pragma unroll
            for (int k = 0; k < 16; k++)
                mkA[k] = mbase[(size_t)(h2u * 32 + (j3 >> 6)) * 16 + k];
            consume(1, Pc0, Pc1);
            Pc0 = mkfrag(peB, pfB, mkB, 0);      // P for tile k+2
            Pc1 = mkfrag(peB + 2, pfB + 2, mkB, 8);
            __syncthreads();
        }
    }

    // Cross-half combine in LDS (reuse staging buffer), then normalize + ELU + store.
    float* cb = (float*)hbh;                 // 4096 + 256 floats = 17.4 KB
    if (h2 == 1) {
        #pragma unroll
        for (int mf = 0; mf < 4; mf++)
            *(f32x4*)&cb[((rg * 4 + mf) * 64 + lane) * 4] = acc[mf];
        cb[4096 + rg * 64 + lane] = accl[0];
    }
    __syncthreads();
    if (h2 == 0) {
        #pragma unroll
        for (int mf = 0; mf < 4; mf++) {
            f32x4 o = *(const f32x4*)&cb[((rg * 4 + mf) * 64 + lane) * 4];
            acc[mf] += o;
        }
        float li = accl[0] + cb[4096 + rg * 64 + lane];
        const float invN = 1.0f / NN;
        float rl = 1.f / li;
        int row = i0 + rg * 16 + am;
        float* orow = outp + (size_t)row * (HH * FF) + h * FF;
        #pragma unroll
        for (int mf = 0; mf < 4; mf++) {
            float4 ov;
            #pragma unroll
            for (int r = 0; r < 4; r++) {
                int f = mf * 16 + aq * 4 + r;
                float v;
                if (li > 0.f) v = acc[mf][r] * rl;
                else          v = hpsum[h * FF + f] * invN;   // all-masked row fallback
                v = v > 0.f ? v : __expf(v) - 1.f;
                f4s(ov, r, v);
            }
            *(float4*)(orow + mf * 16 + aq * 4) = ov;
        }
    }
}

extern "C" void kernel_launch(void* const* d_in, const int* in_sizes, int n_in,
                              void* d_out, int out_size, void* d_ws, size_t ws_size,
                              hipStream_t stream) {
    const float* hmat = (const float*)d_in[0];
    const int*   adj  = (const int*)d_in[1];
    const float* W    = (const float*)d_in[2];
    const float* a    = (const float*)d_in[3];
    float* out = (float*)d_out;

    char* ws = (char*)d_ws;
    unsigned short* hpT_hi = (unsigned short*)(ws);                 // 4 MB
    unsigned long long* adjm = (unsigned long long*)(ws + (4u << 20)); // 2 MB
    unsigned short* wt_hi  = (unsigned short*)(ws + (6u << 20));    // 512 KB
    unsigned short* wt_lo  = (unsigned short*)(ws + (6u << 20) + (512u << 10));
    float* fs    = (float*)(ws + (7u << 20));                       // 128 KB
    float* ejs   = (float*)(ws + (7u << 20) + (128u << 10));        // 128 KB
    unsigned* mxkey = (unsigned*)(ws + (7u << 20) + (256u << 10));  // 64 B
    float* hpsum = (float*)(mxkey + 16);                            // 2 KB
    float* fjs   = (float*)(ws + (7u << 20) + (384u << 10));        // 128 KB
    unsigned short* h_hi = (unsigned short*)(ws + (8u << 20));      // 4 MB
    unsigned short* h_lo = (unsigned short*)(ws + (12u << 20));     // 4 MB

    k_prep   <<<dim3(2369),          256, 0, stream>>>(adj, W, hmat, adjm, wt_hi, wt_lo,
                                                       h_hi, h_lo, mxkey, hpsum);
    k_hp_mfma<<<dim3(64, 8),         256, 0, stream>>>(h_hi, h_lo, wt_hi, wt_lo, a,
                                                       hpT_hi, fs, ejs, fjs, hpsum, mxkey);
    k_attn   <<<dim3(NN / 64, HH),   512, 0, stream>>>(fs, ejs, fjs, mxkey, adjm,
                                                       hpT_hi, hpsum, out);
}

// Round 9
// 191.146 us; speedup vs baseline: 1.0071x; 1.0029x over previous
//
#include <hip/hip_runtime.h>

#define NN 4096
#define DD 512
#define HH 8
#define FF 64
#define LRELU_ALPHA 0.2f
#define SP 72   // LDS row stride in bf16 elems
#define JCHUNK 2048   // per-wave-half j-range

typedef __attribute__((ext_vector_type(8))) short bf16x8;
typedef __attribute__((ext_vector_type(4))) float f32x4;

__device__ __forceinline__ float f4c(const float4& v, int k) {
    return k == 0 ? v.x : (k == 1 ? v.y : (k == 2 ? v.z : v.w));
}
__device__ __forceinline__ void f4s(float4& v, int k, float x) {
    if (k == 0) v.x = x; else if (k == 1) v.y = x; else if (k == 2) v.z = x; else v.w = x;
}
__device__ __forceinline__ unsigned short f2bf(float x) {   // RNE float->bf16
    unsigned u = __float_as_uint(x);
    return (unsigned short)((u + 0x7fffu + ((u >> 16) & 1u)) >> 16);
}
__device__ __forceinline__ float bf2f(unsigned short h) {
    return __uint_as_float(((unsigned)h) << 16);
}
// monotone float<->uint key for atomicMax on arbitrary-sign floats
__device__ __forceinline__ unsigned fkey(float x) {
    unsigned u = __float_as_uint(x);
    return (u & 0x80000000u) ? ~u : (u | 0x80000000u);
}
__device__ __forceinline__ float funkey(unsigned k) {
    unsigned u = (k & 0x80000000u) ? (k ^ 0x80000000u) : ~k;
    return __uint_as_float(u);
}

// ================= Kernel 1: fused prep (verified round 6/8) =================
// [0,2048)     : adjacency -> lane-indexed 64-bit MFMA masks adjm[g][t][16]
// [2048,2112)  : split+transpose W -> wt_hi/wt_lo [h][f][d]
// [2112,2368)  : one-shot hi/lo split of hmat -> h_hi/h_lo [n][d] bf16
// 2368         : zero mxkey + hpsum
__global__ __launch_bounds__(256) void k_prep(const int* __restrict__ adj,
                                              const float* __restrict__ W,
                                              const float* __restrict__ hmat,
                                              unsigned long long* __restrict__ adjm,
                                              unsigned short* __restrict__ wt_hi,
                                              unsigned short* __restrict__ wt_lo,
                                              unsigned short* __restrict__ h_hi,
                                              unsigned short* __restrict__ h_lo,
                                              unsigned* __restrict__ mxkey,
                                              float* __restrict__ hpsum) {
    __shared__ unsigned long long shbuf[2080];   // 16640 B, aliased per branch
    int b = blockIdx.x, t = threadIdx.x;
    if (b < 2048) {
        int g = b >> 3, cs = b & 7;
        int r0 = g * 16;
        int lane = t & 63, wv = t >> 6;
        unsigned long long (*w64)[9] = (unsigned long long(*)[9])shbuf;
        // phase 1: coalesced row-pack of 16 rows x 512 cols into LDS words
        for (int r = 0; r < 16; r++) {
            #pragma unroll
            for (int q = 0; q < 2; q++) {
                int col = cs * 512 + q * 256 + t;
                unsigned long long m = __ballot(adj[(size_t)(r0 + r) * NN + col] > 0);
                if (lane == 0) w64[r][q * 4 + wv] = m;
            }
        }
        __syncthreads();
        // phase 2: transpose-repack into lane-indexed MFMA masks via ballot
        for (int tl = wv; tl < 8; tl += 4) {
            unsigned long long wbits = w64[lane & 15][tl];
            unsigned long long my = 0;
            #pragma unroll
            for (int k = 0; k < 16; k++) {
                int shv = 32 * (k >> 3) + 8 * (lane >> 4) + (k & 7);
                unsigned long long bal = __ballot((unsigned)((wbits >> shv) & 1ULL));
                if (lane == k) my = bal;
            }
            if (lane < 16)
                adjm[((size_t)g * 64 + cs * 8 + tl) * 16 + lane] = my;
        }
    } else if (b < 2112) {
        float (*tile)[65] = (float(*)[65])shbuf;
        int idx = b - 2048;
        int h = idx >> 3;
        int d0 = (idx & 7) * 64;
        #pragma unroll
        for (int kidx = 0; kidx < 4; kidx++) {
            int id = t + 256 * kidx;
            int dd = id >> 4, f4i = (id & 15) * 4;
            float4 v = *(const float4*)(W + ((size_t)(h * DD + d0 + dd)) * FF + f4i);
            tile[dd][f4i] = v.x; tile[dd][f4i + 1] = v.y;
            tile[dd][f4i + 2] = v.z; tile[dd][f4i + 3] = v.w;
        }
        __syncthreads();
        int f = t >> 2, c = (t & 3) * 16;
        union { unsigned short s[16]; uint4 v[2]; } hb, lb;
        #pragma unroll
        for (int q = 0; q < 16; q++) {
            float v = tile[c + q][f];
            unsigned short hi = f2bf(v);
            hb.s[q] = hi;
            lb.s[q] = f2bf(v - bf2f(hi));
        }
        uint4* dh = (uint4*)(wt_hi + ((size_t)h * FF + f) * DD + d0 + c);
        uint4* dl = (uint4*)(wt_lo + ((size_t)h * FF + f) * DD + d0 + c);
        dh[0] = hb.v[0]; dh[1] = hb.v[1];
        dl[0] = lb.v[0]; dl[1] = lb.v[1];
    } else if (b < 2368) {
        // one-shot hi/lo split of hmat (bit-identical to the old in-k_hp split)
        int idx = b - 2112;                  // 0..255, 16 rows each
        int row = idx * 16 + (t >> 4);
        int c0 = (t & 15) * 32;
        const float* src = hmat + (size_t)row * DD + c0;
        #pragma unroll
        for (int half = 0; half < 2; half++) {
            float4 p0 = *(const float4*)(src + half * 16);
            float4 p1 = *(const float4*)(src + half * 16 + 4);
            float4 p2 = *(const float4*)(src + half * 16 + 8);
            float4 p3 = *(const float4*)(src + half * 16 + 12);
            union { unsigned short s[16]; uint4 v[2]; } hb, lb;
            #pragma unroll
            for (int q = 0; q < 16; q++) {
                float v = q < 4 ? f4c(p0, q) : q < 8 ? f4c(p1, q - 4)
                          : q < 12 ? f4c(p2, q - 8) : f4c(p3, q - 12);
                unsigned short hi = f2bf(v);
                hb.s[q] = hi;
                lb.s[q] = f2bf(v - bf2f(hi));
            }
            uint4* dh = (uint4*)(h_hi + (size_t)row * DD + c0 + half * 16);
            uint4* dl = (uint4*)(h_lo + (size_t)row * DD + c0 + half * 16);
            dh[0] = hb.v[0]; dh[1] = hb.v[1];
            dl[0] = lb.v[0]; dl[1] = lb.v[1];
        }
    } else {
        if (t < 16) mxkey[t] = 0u;
        hpsum[t] = 0.f;
        hpsum[t + 256] = 0.f;
    }
}

// ================= Kernel 2: hp GEMM (verified round 8: emits Ej/Fj exp factors) ========
__global__ __launch_bounds__(256) void k_hp_mfma(const unsigned short* __restrict__ hhi,
                                                 const unsigned short* __restrict__ hlo,
                                                 const unsigned short* __restrict__ whi,
                                                 const unsigned short* __restrict__ wlo,
                                                 const float* __restrict__ a,
                                                 unsigned short* __restrict__ hpT_hi,
                                                 float* __restrict__ fs,
                                                 float* __restrict__ ejs,
                                                 float* __restrict__ fjs,
                                                 float* __restrict__ hpsum,
                                                 unsigned* __restrict__ mxkey) {
    __shared__ char smem[4 * 64 * SP * 2];   // 36864 B
    unsigned short* ah = (unsigned short*)smem;
    unsigned short* al = ah + 64 * SP;
    unsigned short* bh = al + 64 * SP;
    unsigned short* bl = bh + 64 * SP;

    int t = threadIdx.x;
    int h = blockIdx.y;
    int n0 = blockIdx.x * 64;
    int lane = t & 63;
    int w = t >> 6;
    int R0 = (w >> 1) * 32, F0 = (w & 1) * 32;
    int am = lane & 15, aq = lane >> 4;
    int sr = t >> 2, sc = (t & 3) * 16;

    const unsigned short* ghh = hhi + (size_t)(n0 + sr) * DD;
    const unsigned short* ghl = hlo + (size_t)(n0 + sr) * DD;
    const unsigned short* gbh = whi + ((size_t)h * FF + sr) * DD;
    const unsigned short* gbl = wlo + ((size_t)h * FF + sr) * DD;

    f32x4 acc[2][2] = {};
    for (int kk = 0; kk < DD; kk += 64) {
        {   // h: pre-split bf16 hi/lo copies
            const uint4* s0 = (const uint4*)(ghh + kk + sc);
            const uint4* s1 = (const uint4*)(ghl + kk + sc);
            uint4 h0 = s0[0], h1 = s0[1], l0 = s1[0], l1 = s1[1];
            *(uint4*)(ah + sr * SP + sc) = h0; *(uint4*)(ah + sr * SP + sc + 8) = h1;
            *(uint4*)(al + sr * SP + sc) = l0; *(uint4*)(al + sr * SP + sc + 8) = l1;
        }
        {
            const uint4* s2 = (const uint4*)(gbh + kk + sc);
            const uint4* s3 = (const uint4*)(gbl + kk + sc);
            uint4 w0 = s2[0], w1 = s2[1], x0 = s3[0], x1 = s3[1];
            *(uint4*)(bh + sr * SP + sc) = w0; *(uint4*)(bh + sr * SP + sc + 8) = w1;
            *(uint4*)(bl + sr * SP + sc) = x0; *(uint4*)(bl + sr * SP + sc + 8) = x1;
        }
        __syncthreads();
        #pragma unroll
        for (int k2 = 0; k2 < 2; k2++) {
            int ko = k2 * 32 + aq * 8;
            bf16x8 a0h = *(const bf16x8*)(ah + (R0 + am) * SP + ko);
            bf16x8 a1h = *(const bf16x8*)(ah + (R0 + 16 + am) * SP + ko);
            bf16x8 a0l = *(const bf16x8*)(al + (R0 + am) * SP + ko);
            bf16x8 a1l = *(const bf16x8*)(al + (R0 + 16 + am) * SP + ko);
            bf16x8 b0h = *(const bf16x8*)(bh + (F0 + am) * SP + ko);
            bf16x8 b1h = *(const bf16x8*)(bh + (F0 + 16 + am) * SP + ko);
            bf16x8 b0l = *(const bf16x8*)(bl + (F0 + am) * SP + ko);
            bf16x8 b1l = *(const bf16x8*)(bl + (F0 + 16 + am) * SP + ko);
            acc[0][0] = __builtin_amdgcn_mfma_f32_16x16x32_bf16(a0h, b0h, acc[0][0], 0, 0, 0);
            acc[0][1] = __builtin_amdgcn_mfma_f32_16x16x32_bf16(a0h, b1h, acc[0][1], 0, 0, 0);
            acc[1][0] = __builtin_amdgcn_mfma_f32_16x16x32_bf16(a1h, b0h, acc[1][0], 0, 0, 0);
            acc[1][1] = __builtin_amdgcn_mfma_f32_16x16x32_bf16(a1h, b1h, acc[1][1], 0, 0, 0);
            acc[0][0] = __builtin_amdgcn_mfma_f32_16x16x32_bf16(a0h, b0l, acc[0][0], 0, 0, 0);
            acc[0][1] = __builtin_amdgcn_mfma_f32_16x16x32_bf16(a0h, b1l, acc[0][1], 0, 0, 0);
            acc[1][0] = __builtin_amdgcn_mfma_f32_16x16x32_bf16(a1h, b0l, acc[1][0], 0, 0, 0);
            acc[1][1] = __builtin_amdgcn_mfma_f32_16x16x32_bf16(a1h, b1l, acc[1][1], 0, 0, 0);
            acc[0][0] = __builtin_amdgcn_mfma_f32_16x16x32_bf16(a0l, b0h, acc[0][0], 0, 0, 0);
            acc[0][1] = __builtin_amdgcn_mfma_f32_16x16x32_bf16(a0l, b1h, acc[0][1], 0, 0, 0);
            acc[1][0] = __builtin_amdgcn_mfma_f32_16x16x32_bf16(a1l, b0h, acc[1][0], 0, 0, 0);
            acc[1][1] = __builtin_amdgcn_mfma_f32_16x16x32_bf16(a1l, b1h, acc[1][1], 0, 0, 0);
        }
        __syncthreads();
    }

    // Epilogue: pack hi/lo to LDS [f][n], store hi, fs (scaled), Ej/Fj, maxfd, hpsum.
    unsigned* tt = (unsigned*)smem;
    float* rs = (float*)(smem + 17408);
    float* rd = rs + 256;
    float* ash = rd + 256;
    if (t < 128) ash[t] = a[h * 2 * FF + t];
    int col = lane & 15, rbase = (lane >> 4) * 4;
    #pragma unroll
    for (int m16 = 0; m16 < 2; m16++) {
        #pragma unroll
        for (int n16 = 0; n16 < 2; n16++) {
            #pragma unroll
            for (int r = 0; r < 4; r++) {
                int nl = R0 + m16 * 16 + rbase + r;
                int f = F0 + n16 * 16 + col;
                float v = acc[m16][n16][r];
                unsigned short hi = f2bf(v);
                unsigned short lo = f2bf(v - bf2f(hi));
                tt[f * 68 + nl] = (unsigned)hi | ((unsigned)lo << 16);
            }
        }
    }
    __syncthreads();
    {
        int f = t >> 2, c = (t & 3) * 16;
        union { unsigned short s[16]; uint4 v[2]; } hb;
        float csum = 0.f;
        #pragma unroll
        for (int q = 0; q < 16; q++) {
            unsigned u = tt[f * 68 + c + q];
            hb.s[q] = (unsigned short)(u & 0xffffu);
            csum += bf2f((unsigned short)(u & 0xffffu)) + bf2f((unsigned short)(u >> 16));
        }
        uint4* dh = (uint4*)(hpT_hi + ((size_t)h * FF + f) * NN + n0 + c);
        dh[0] = hb.v[0]; dh[1] = hb.v[1];
        csum += __shfl_xor(csum, 1);
        csum += __shfl_xor(csum, 2);
        if ((t & 3) == 0) unsafeAtomicAdd(hpsum + h * FF + f, csum);
    }
    {
        int n = t & 63, g = t >> 6;
        float fsp = 0.f, fdp = 0.f;
        #pragma unroll
        for (int q = 0; q < 16; q++) {
            int f = g * 16 + q;
            unsigned u = tt[f * 68 + n];
            float v = bf2f((unsigned short)(u & 0xffffu)) + bf2f((unsigned short)(u >> 16));
            fsp += v * ash[f];
            fdp += v * ash[64 + f];
        }
        rs[g * 64 + n] = fsp;
        rd[g * 64 + n] = fdp;
    }
    __syncthreads();
    if (t < 64) {
        const float LOG2E = 1.44269504f;
        float fdv = (rd[t] + rd[64 + t] + rd[128 + t] + rd[192 + t]) * LOG2E;
        fs[(size_t)h * NN + n0 + t] = (rs[t] + rs[64 + t] + rs[128 + t] + rs[192 + t]) * LOG2E;
        ejs[(size_t)h * NN + n0 + t] = __builtin_amdgcn_exp2f(fdv);
        fjs[(size_t)h * NN + n0 + t] = __builtin_amdgcn_exp2f(LRELU_ALPHA * fdv);
        unsigned key = fkey(fdv);
        #pragma unroll
        for (int off = 32; off; off >>= 1) key = max(key, (unsigned)__shfl_xor((int)key, off));
        if (t == 0) atomicMax(mxkey + h, key);
    }
}

// ================= Kernel 3: attention — ROUND-6 SCHEDULE + exp-free scores ============
// grid (NN/64, HH), 512 threads = 8 waves. Wave w: j-half h2 = w>>2 (2048 cols),
// row-group rg = w&3 (16 i-rows). EXACT round-6 loop order (stage_load top, consume,
// stage_write, mkfrag, one barrier). Score: e = max(EA*Ej, EC*Fj) — no exp2 in loop.
__global__ __launch_bounds__(512) void k_attn(const float* __restrict__ fs,
                                              const float* __restrict__ ejs,
                                              const float* __restrict__ fjs,
                                              const unsigned* __restrict__ mxkey,
                                              const unsigned long long* __restrict__ adjm,
                                              const unsigned short* __restrict__ hpT_hi,
                                              const float* __restrict__ hpsum,
                                              float* __restrict__ outp) {
    __shared__ unsigned short hbh[2][2][64 * SP];   // [dbuf][j-half][f*SP+j] = 36864 B

    int t = threadIdx.x;
    int h = blockIdx.y;
    int i0 = blockIdx.x * 64;
    int lane = t & 63;
    int w = t >> 6;              // 0..7
    int h2 = w >> 2;             // j-half
    int rg = w & 3;              // row-group
    int am = lane & 15, aq = lane >> 4;
    int th = t >> 8;             // staging: which half's tile this thread fills
    int ts = t & 255;
    int sr = ts >> 2, sc = (ts & 3) * 16;

    // per-row exp factors (scaled/log2 domain): e_pos = EA*Ej, e_neg = EC*Fj
    float mfdL = funkey(mxkey[h]);
    float fsv = fs[(size_t)h * NN + i0 + rg * 16 + am];
    float sL = fsv + mfdL;
    float mrL = fmaxf(sL, LRELU_ALPHA * sL);
    float EA = __builtin_amdgcn_exp2f(fsv - mrL);
    float EC = __builtin_amdgcn_exp2f(LRELU_ALPHA * fsv - mrL);

    int rgu = __builtin_amdgcn_readfirstlane(rg);
    int h2u = __builtin_amdgcn_readfirstlane(h2);
    const unsigned long long* mbase = adjm + ((size_t)(blockIdx.x * 4 + rgu) * 64) * 16;
    const unsigned short* gH = hpT_hi + (size_t)h * FF * NN;
    const float* ejh = ejs + (size_t)h * NN + (size_t)h2u * JCHUNK;
    const float* fjh = fjs + (size_t)h * NN + (size_t)h2u * JCHUNK;

    f32x4 acc[4] = {};
    f32x4 accl = {};
    bf16x8 ones;
    #pragma unroll
    for (int i = 0; i < 8; i++) ones[i] = (short)0x3f80;   // bf16 1.0

    auto stage_load = [&](int j0, uint4& v0, uint4& v1) {   // j0 relative to half
        const uint4* s = (const uint4*)(gH + (size_t)sr * NN + th * JCHUNK + j0 + sc);
        v0 = s[0]; v1 = s[1];
    };
    auto stage_write = [&](int buf, uint4 v0, uint4 v1) {
        *(uint4*)(&hbh[buf][th][sr * SP + sc]) = v0;
        *(uint4*)(&hbh[buf][th][sr * SP + sc + 8]) = v1;
    };
    auto ejf_load = [&](int j0, float4* pe, float4* pf) {
        pe[0] = *(const float4*)(ejh + j0 + aq * 8);
        pe[1] = *(const float4*)(ejh + j0 + aq * 8 + 4);
        pe[2] = *(const float4*)(ejh + j0 + 32 + aq * 8);
        pe[3] = *(const float4*)(ejh + j0 + 32 + aq * 8 + 4);
        pf[0] = *(const float4*)(fjh + j0 + aq * 8);
        pf[1] = *(const float4*)(fjh + j0 + aq * 8 + 4);
        pf[2] = *(const float4*)(fjh + j0 + 32 + aq * 8);
        pf[3] = *(const float4*)(fjh + j0 + 32 + aq * 8 + 4);
    };
    // 8 scores -> one bf16x8 B-fragment; masks are wave-uniform 64-bit lane masks
    auto mkfrag = [&](const float4* pe, const float4* pf,
                      const unsigned long long* mk, int off) -> bf16x8 {
        unsigned eu[8];
        #pragma unroll
        for (int q = 0; q < 2; q++) {
            float4 ev4 = pe[q], fv4 = pf[q];
            #pragma unroll
            for (int bq = 0; bq < 4; bq++) {
                float e = fmaxf(EA * f4c(ev4, bq), EC * f4c(fv4, bq));
                unsigned r;
                asm("v_cndmask_b32 %0, 0, %1, %2"
                    : "=v"(r) : "v"(e), "s"(mk[off + q * 4 + bq]));
                eu[q * 4 + bq] = r;
            }
        }
        union { unsigned u[4]; bf16x8 v; } pk;
        pk.u[0] = __builtin_amdgcn_perm(eu[1], eu[0], 0x07060302);
        pk.u[1] = __builtin_amdgcn_perm(eu[3], eu[2], 0x07060302);
        pk.u[2] = __builtin_amdgcn_perm(eu[5], eu[4], 0x07060302);
        pk.u[3] = __builtin_amdgcn_perm(eu[7], eu[6], 0x07060302);
        return pk.v;
    };

    bf16x8 Pc0, Pc1;
    {   // prologue: tile 0 of each half
        uint4 v0, v1; float4 pe[4], pf[4];
        stage_load(0, v0, v1);
        ejf_load(0, pe, pf);
        unsigned long long mk[16];
        #pragma unroll
        for (int k = 0; k < 16; k++) mk[k] = mbase[(size_t)(h2u * 32) * 16 + k];
        Pc0 = mkfrag(pe, pf, mk, 0);
        Pc1 = mkfrag(pe + 2, pf + 2, mk, 8);
        stage_write(0, v0, v1);
        __syncthreads();
    }

    for (int j0 = 0; j0 < JCHUNK; j0 += 64) {
        int cur = (j0 >> 6) & 1;
        int jn = (j0 + 64) & (JCHUNK - 1);   // wraps on last iter; produce is harmless then
        uint4 v0, v1; float4 pe[4], pf[4];
        stage_load(jn, v0, v1);              // issue next-tile loads early (T14)
        ejf_load(jn, pe, pf);
        unsigned long long mk[16];
        #pragma unroll
        for (int k = 0; k < 16; k++) mk[k] = mbase[(size_t)(h2u * 32 + (jn >> 6)) * 16 + k];

        // consume current tile of this wave's half: hp A-frags from LDS, P from registers
        #pragma unroll
        for (int k2 = 0; k2 < 2; k2++) {
            int ko = k2 * 32 + aq * 8;
            bf16x8 x0 = *(const bf16x8*)(&hbh[cur][h2][(am)      * SP + ko]);
            bf16x8 x1 = *(const bf16x8*)(&hbh[cur][h2][(am + 16) * SP + ko]);
            bf16x8 x2 = *(const bf16x8*)(&hbh[cur][h2][(am + 32) * SP + ko]);
            bf16x8 x3 = *(const bf16x8*)(&hbh[cur][h2][(am + 48) * SP + ko]);
            bf16x8 P = k2 ? Pc1 : Pc0;
            acc[0] = __builtin_amdgcn_mfma_f32_16x16x32_bf16(x0, P, acc[0], 0, 0, 0);
            acc[1] = __builtin_amdgcn_mfma_f32_16x16x32_bf16(x1, P, acc[1], 0, 0, 0);
            acc[2] = __builtin_amdgcn_mfma_f32_16x16x32_bf16(x2, P, acc[2], 0, 0, 0);
            acc[3] = __builtin_amdgcn_mfma_f32_16x16x32_bf16(x3, P, acc[3], 0, 0, 0);
            accl   = __builtin_amdgcn_mfma_f32_16x16x32_bf16(ones, P, accl, 0, 0, 0);
        }

        stage_write(cur ^ 1, v0, v1);        // write next hp tile (other buffer)
        Pc0 = mkfrag(pe, pf, mk, 0);
        Pc1 = mkfrag(pe + 2, pf + 2, mk, 8);
        __syncthreads();
    }

    // Cross-half combine in LDS (reuse staging buffer), then normalize + ELU + store.
    float* cb = (float*)hbh;                 // 4096 + 256 floats = 17.4 KB
    if (h2 == 1) {
        #pragma unroll
        for (int mf = 0; mf < 4; mf++)
            *(f32x4*)&cb[((rg * 4 + mf) * 64 + lane) * 4] = acc[mf];
        cb[4096 + rg * 64 + lane] = accl[0];
    }
    __syncthreads();
    if (h2 == 0) {
        #pragma unroll
        for (int mf = 0; mf < 4; mf++) {
            f32x4 o = *(const f32x4*)&cb[((rg * 4 + mf) * 64 + lane) * 4];
            acc[mf] += o;
        }
        float li = accl[0] + cb[4096 + rg * 64 + lane];
        const float invN = 1.0f / NN;
        float rl = 1.f / li;
        int row = i0 + rg * 16 + am;
        float* orow = outp + (size_t)row * (HH * FF) + h * FF;
        #pragma unroll
        for (int mf = 0; mf < 4; mf++) {
            float4 ov;
            #pragma unroll
            for (int r = 0; r < 4; r++) {
                int f = mf * 16 + aq * 4 + r;
                float v;
                if (li > 0.f) v = acc[mf][r] * rl;
                else          v = hpsum[h * FF + f] * invN;   // all-masked row fallback
                v = v > 0.f ? v : __expf(v) - 1.f;
                f4s(ov, r, v);
            }
            *(float4*)(orow + mf * 16 + aq * 4) = ov;
        }
    }
}

extern "C" void kernel_launch(void* const* d_in, const int* in_sizes, int n_in,
                              void* d_out, int out_size, void* d_ws, size_t ws_size,
                              hipStream_t stream) {
    const float* hmat = (const float*)d_in[0];
    const int*   adj  = (const int*)d_in[1];
    const float* W    = (const float*)d_in[2];
    const float* a    = (const float*)d_in[3];
    float* out = (float*)d_out;

    char* ws = (char*)d_ws;
    unsigned short* hpT_hi = (unsigned short*)(ws);                 // 4 MB
    unsigned long long* adjm = (unsigned long long*)(ws + (4u << 20)); // 2 MB
    unsigned short* wt_hi  = (unsigned short*)(ws + (6u << 20));    // 512 KB
    unsigned short* wt_lo  = (unsigned short*)(ws + (6u << 20) + (512u << 10));
    float* fs    = (float*)(ws + (7u << 20));                       // 128 KB
    float* ejs   = (float*)(ws + (7u << 20) + (128u << 10));        // 128 KB
    unsigned* mxkey = (unsigned*)(ws + (7u << 20) + (256u << 10));  // 64 B
    float* hpsum = (float*)(mxkey + 16);                            // 2 KB
    float* fjs   = (float*)(ws + (7u << 20) + (384u << 10));        // 128 KB
    unsigned short* h_hi = (unsigned short*)(ws + (8u << 20));      // 4 MB
    unsigned short* h_lo = (unsigned short*)(ws + (12u << 20));     // 4 MB

    k_prep   <<<dim3(2369),          256, 0, stream>>>(adj, W, hmat, adjm, wt_hi, wt_lo,
                                                       h_hi, h_lo, mxkey, hpsum);
    k_hp_mfma<<<dim3(64, 8),         256, 0, stream>>>(h_hi, h_lo, wt_hi, wt_lo, a,
                                                       hpT_hi, fs, ejs, fjs, hpsum, mxkey);
    k_attn   <<<dim3(NN / 64, HH),   512, 0, stream>>>(fs, ejs, fjs, mxkey, adjm,
                                                       hpT_hi, hpsum, out);
}

// Round 11
// 173.155 us; speedup vs baseline: 1.1118x; 1.1039x over previous
//
#include <hip/hip_runtime.h>

#define NN 4096
#define DD 512
#define HH 8
#define FF 64
#define LRELU_ALPHA 0.2f
#define SP 72   // LDS row stride in bf16 elems
#define JSPLIT 2
#define JCHUNK (NN / JSPLIT)

typedef __attribute__((ext_vector_type(8))) short bf16x8;
typedef __attribute__((ext_vector_type(4))) float f32x4;

__device__ __forceinline__ float f4c(const float4& v, int k) {
    return k == 0 ? v.x : (k == 1 ? v.y : (k == 2 ? v.z : v.w));
}
__device__ __forceinline__ void f4s(float4& v, int k, float x) {
    if (k == 0) v.x = x; else if (k == 1) v.y = x; else if (k == 2) v.z = x; else v.w = x;
}
__device__ __forceinline__ unsigned short f2bf(float x) {   // RNE float->bf16
    unsigned u = __float_as_uint(x);
    return (unsigned short)((u + 0x7fffu + ((u >> 16) & 1u)) >> 16);
}
__device__ __forceinline__ float bf2f(unsigned short h) {
    return __uint_as_float(((unsigned)h) << 16);
}
// monotone float<->uint key for atomicMax on arbitrary-sign floats
__device__ __forceinline__ unsigned fkey(float x) {
    unsigned u = __float_as_uint(x);
    return (u & 0x80000000u) ? ~u : (u | 0x80000000u);
}
__device__ __forceinline__ float funkey(unsigned k) {
    unsigned u = (k & 0x80000000u) ? (k ^ 0x80000000u) : ~k;
    return __uint_as_float(u);
}

// ================= Kernel 1: fused prep =================
// [0,2048)     : adjacency -> lane-indexed 64-bit MFMA masks adjm[g][t][16]
//                block b: g = b>>3 (16-row group), cs = b&7 (512-col segment).
// [2048,2112)  : split+transpose W -> wt_hi/wt_lo [h][f][d]
// [2112,2368)  : one-shot hi/lo split of hmat -> h_hi/h_lo [n][d] bf16
// 2368         : zero mxkey + hpsum
__global__ __launch_bounds__(256) void k_prep(const int* __restrict__ adj,
                                              const float* __restrict__ W,
                                              const float* __restrict__ hmat,
                                              unsigned long long* __restrict__ adjm,
                                              unsigned short* __restrict__ wt_hi,
                                              unsigned short* __restrict__ wt_lo,
                                              unsigned short* __restrict__ h_hi,
                                              unsigned short* __restrict__ h_lo,
                                              unsigned* __restrict__ mxkey,
                                              float* __restrict__ hpsum) {
    __shared__ unsigned long long shbuf[2080];   // 16640 B, aliased per branch
    int b = blockIdx.x, t = threadIdx.x;
    if (b < 2048) {
        int g = b >> 3, cs = b & 7;
        int r0 = g * 16;
        int lane = t & 63, wv = t >> 6;
        unsigned long long (*w64)[9] = (unsigned long long(*)[9])shbuf;
        // phase 1: coalesced row-pack of 16 rows x 512 cols into LDS words
        for (int r = 0; r < 16; r++) {
            #pragma unroll
            for (int q = 0; q < 2; q++) {
                int col = cs * 512 + q * 256 + t;
                unsigned long long m = __ballot(adj[(size_t)(r0 + r) * NN + col] > 0);
                if (lane == 0) w64[r][q * 4 + wv] = m;
            }
        }
        __syncthreads();
        // phase 2: transpose-repack into lane-indexed MFMA masks via ballot
        for (int tl = wv; tl < 8; tl += 4) {
            unsigned long long wbits = w64[lane & 15][tl];
            unsigned long long my = 0;
            #pragma unroll
            for (int k = 0; k < 16; k++) {
                int shv = 32 * (k >> 3) + 8 * (lane >> 4) + (k & 7);
                unsigned long long bal = __ballot((unsigned)((wbits >> shv) & 1ULL));
                if (lane == k) my = bal;
            }
            if (lane < 16)
                adjm[((size_t)g * 64 + cs * 8 + tl) * 16 + lane] = my;
        }
    } else if (b < 2112) {
        float (*tile)[65] = (float(*)[65])shbuf;
        int idx = b - 2048;
        int h = idx >> 3;
        int d0 = (idx & 7) * 64;
        #pragma unroll
        for (int kidx = 0; kidx < 4; kidx++) {
            int id = t + 256 * kidx;
            int dd = id >> 4, f4i = (id & 15) * 4;
            float4 v = *(const float4*)(W + ((size_t)(h * DD + d0 + dd)) * FF + f4i);
            tile[dd][f4i] = v.x; tile[dd][f4i + 1] = v.y;
            tile[dd][f4i + 2] = v.z; tile[dd][f4i + 3] = v.w;
        }
        __syncthreads();
        int f = t >> 2, c = (t & 3) * 16;
        union { unsigned short s[16]; uint4 v[2]; } hb, lb;
        #pragma unroll
        for (int q = 0; q < 16; q++) {
            float v = tile[c + q][f];
            unsigned short hi = f2bf(v);
            hb.s[q] = hi;
            lb.s[q] = f2bf(v - bf2f(hi));
        }
        uint4* dh = (uint4*)(wt_hi + ((size_t)h * FF + f) * DD + d0 + c);
        uint4* dl = (uint4*)(wt_lo + ((size_t)h * FF + f) * DD + d0 + c);
        dh[0] = hb.v[0]; dh[1] = hb.v[1];
        dl[0] = lb.v[0]; dl[1] = lb.v[1];
    } else if (b < 2368) {
        // one-shot hi/lo split of hmat (bit-identical to the old in-k_hp split)
        int idx = b - 2112;                  // 0..255, 16 rows each
        int row = idx * 16 + (t >> 4);
        int c0 = (t & 15) * 32;
        const float* src = hmat + (size_t)row * DD + c0;
        #pragma unroll
        for (int half = 0; half < 2; half++) {
            float4 p0 = *(const float4*)(src + half * 16);
            float4 p1 = *(const float4*)(src + half * 16 + 4);
            float4 p2 = *(const float4*)(src + half * 16 + 8);
            float4 p3 = *(const float4*)(src + half * 16 + 12);
            union { unsigned short s[16]; uint4 v[2]; } hb, lb;
            #pragma unroll
            for (int q = 0; q < 16; q++) {
                float v = q < 4 ? f4c(p0, q) : q < 8 ? f4c(p1, q - 4)
                          : q < 12 ? f4c(p2, q - 8) : f4c(p3, q - 12);
                unsigned short hi = f2bf(v);
                hb.s[q] = hi;
                lb.s[q] = f2bf(v - bf2f(hi));
            }
            uint4* dh = (uint4*)(h_hi + (size_t)row * DD + c0 + half * 16);
            uint4* dl = (uint4*)(h_lo + (size_t)row * DD + c0 + half * 16);
            dh[0] = hb.v[0]; dh[1] = hb.v[1];
            dl[0] = lb.v[0]; dl[1] = lb.v[1];
        }
    } else {
        if (t < 16) mxkey[t] = 0u;
        hpsum[t] = 0.f;
        hpsum[t + 256] = 0.f;
    }
}

// ================= Kernel 2: hp GEMM (pre-split h_hi/h_lo; MFMA 3-product) ========
// Staging is pure uint4 copies (split hoisted to k_prep). MFMA/epilogue unchanged.
__global__ __launch_bounds__(256) void k_hp_mfma(const unsigned short* __restrict__ hhi,
                                                 const unsigned short* __restrict__ hlo,
                                                 const unsigned short* __restrict__ whi,
                                                 const unsigned short* __restrict__ wlo,
                                                 const float* __restrict__ a,
                                                 unsigned short* __restrict__ hpT_hi,
                                                 float* __restrict__ fs,
                                                 float* __restrict__ fd,
                                                 float* __restrict__ hpsum,
                                                 unsigned* __restrict__ mxkey) {
    __shared__ char smem[4 * 64 * SP * 2];   // 36864 B
    unsigned short* ah = (unsigned short*)smem;
    unsigned short* al = ah + 64 * SP;
    unsigned short* bh = al + 64 * SP;
    unsigned short* bl = bh + 64 * SP;

    int t = threadIdx.x;
    int h = blockIdx.y;
    int n0 = blockIdx.x * 64;
    int lane = t & 63;
    int w = t >> 6;
    int R0 = (w >> 1) * 32, F0 = (w & 1) * 32;
    int am = lane & 15, aq = lane >> 4;
    int sr = t >> 2, sc = (t & 3) * 16;

    const unsigned short* ghh = hhi + (size_t)(n0 + sr) * DD;
    const unsigned short* ghl = hlo + (size_t)(n0 + sr) * DD;
    const unsigned short* gbh = whi + ((size_t)h * FF + sr) * DD;
    const unsigned short* gbl = wlo + ((size_t)h * FF + sr) * DD;

    f32x4 acc[2][2] = {};
    for (int kk = 0; kk < DD; kk += 64) {
        {   // h: pre-split bf16 hi/lo copies
            const uint4* s0 = (const uint4*)(ghh + kk + sc);
            const uint4* s1 = (const uint4*)(ghl + kk + sc);
            uint4 h0 = s0[0], h1 = s0[1], l0 = s1[0], l1 = s1[1];
            *(uint4*)(ah + sr * SP + sc) = h0; *(uint4*)(ah + sr * SP + sc + 8) = h1;
            *(uint4*)(al + sr * SP + sc) = l0; *(uint4*)(al + sr * SP + sc + 8) = l1;
        }
        {
            const uint4* s2 = (const uint4*)(gbh + kk + sc);
            const uint4* s3 = (const uint4*)(gbl + kk + sc);
            uint4 w0 = s2[0], w1 = s2[1], x0 = s3[0], x1 = s3[1];
            *(uint4*)(bh + sr * SP + sc) = w0; *(uint4*)(bh + sr * SP + sc + 8) = w1;
            *(uint4*)(bl + sr * SP + sc) = x0; *(uint4*)(bl + sr * SP + sc + 8) = x1;
        }
        __syncthreads();
        #pragma unroll
        for (int k2 = 0; k2 < 2; k2++) {
            int ko = k2 * 32 + aq * 8;
            bf16x8 a0h = *(const bf16x8*)(ah + (R0 + am) * SP + ko);
            bf16x8 a1h = *(const bf16x8*)(ah + (R0 + 16 + am) * SP + ko);
            bf16x8 a0l = *(const bf16x8*)(al + (R0 + am) * SP + ko);
            bf16x8 a1l = *(const bf16x8*)(al + (R0 + 16 + am) * SP + ko);
            bf16x8 b0h = *(const bf16x8*)(bh + (F0 + am) * SP + ko);
            bf16x8 b1h = *(const bf16x8*)(bh + (F0 + 16 + am) * SP + ko);
            bf16x8 b0l = *(const bf16x8*)(bl + (F0 + am) * SP + ko);
            bf16x8 b1l = *(const bf16x8*)(bl + (F0 + 16 + am) * SP + ko);
            acc[0][0] = __builtin_amdgcn_mfma_f32_16x16x32_bf16(a0h, b0h, acc[0][0], 0, 0, 0);
            acc[0][1] = __builtin_amdgcn_mfma_f32_16x16x32_bf16(a0h, b1h, acc[0][1], 0, 0, 0);
            acc[1][0] = __builtin_amdgcn_mfma_f32_16x16x32_bf16(a1h, b0h, acc[1][0], 0, 0, 0);
            acc[1][1] = __builtin_amdgcn_mfma_f32_16x16x32_bf16(a1h, b1h, acc[1][1], 0, 0, 0);
            acc[0][0] = __builtin_amdgcn_mfma_f32_16x16x32_bf16(a0h, b0l, acc[0][0], 0, 0, 0);
            acc[0][1] = __builtin_amdgcn_mfma_f32_16x16x32_bf16(a0h, b1l, acc[0][1], 0, 0, 0);
            acc[1][0] = __builtin_amdgcn_mfma_f32_16x16x32_bf16(a1h, b0l, acc[1][0], 0, 0, 0);
            acc[1][1] = __builtin_amdgcn_mfma_f32_16x16x32_bf16(a1h, b1l, acc[1][1], 0, 0, 0);
            acc[0][0] = __builtin_amdgcn_mfma_f32_16x16x32_bf16(a0l, b0h, acc[0][0], 0, 0, 0);
            acc[0][1] = __builtin_amdgcn_mfma_f32_16x16x32_bf16(a0l, b1h, acc[0][1], 0, 0, 0);
            acc[1][0] = __builtin_amdgcn_mfma_f32_16x16x32_bf16(a1l, b0h, acc[1][0], 0, 0, 0);
            acc[1][1] = __builtin_amdgcn_mfma_f32_16x16x32_bf16(a1l, b1h, acc[1][1], 0, 0, 0);
        }
        __syncthreads();
    }

    // Epilogue: pack hi/lo to LDS [f][n], store hi, fs/fd (scaled by LOG2E), maxfd, hpsum.
    unsigned* tt = (unsigned*)smem;
    float* rs = (float*)(smem + 17408);
    float* rd = rs + 256;
    float* ash = rd + 256;
    if (t < 128) ash[t] = a[h * 2 * FF + t];
    int col = lane & 15, rbase = (lane >> 4) * 4;
    #pragma unroll
    for (int m16 = 0; m16 < 2; m16++) {
        #pragma unroll
        for (int n16 = 0; n16 < 2; n16++) {
            #pragma unroll
            for (int r = 0; r < 4; r++) {
                int nl = R0 + m16 * 16 + rbase + r;
                int f = F0 + n16 * 16 + col;
                float v = acc[m16][n16][r];
                unsigned short hi = f2bf(v);
                unsigned short lo = f2bf(v - bf2f(hi));
                tt[f * 68 + nl] = (unsigned)hi | ((unsigned)lo << 16);
            }
        }
    }
    __syncthreads();
    {
        int f = t >> 2, c = (t & 3) * 16;
        union { unsigned short s[16]; uint4 v[2]; } hb;
        float csum = 0.f;
        #pragma unroll
        for (int q = 0; q < 16; q++) {
            unsigned u = tt[f * 68 + c + q];
            hb.s[q] = (unsigned short)(u & 0xffffu);
            csum += bf2f((unsigned short)(u & 0xffffu)) + bf2f((unsigned short)(u >> 16));
        }
        uint4* dh = (uint4*)(hpT_hi + ((size_t)h * FF + f) * NN + n0 + c);
        dh[0] = hb.v[0]; dh[1] = hb.v[1];
        csum += __shfl_xor(csum, 1);
        csum += __shfl_xor(csum, 2);
        if ((t & 3) == 0) unsafeAtomicAdd(hpsum + h * FF + f, csum);
    }
    {
        int n = t & 63, g = t >> 6;
        float fsp = 0.f, fdp = 0.f;
        #pragma unroll
        for (int q = 0; q < 16; q++) {
            int f = g * 16 + q;
            unsigned u = tt[f * 68 + n];
            float v = bf2f((unsigned short)(u & 0xffffu)) + bf2f((unsigned short)(u >> 16));
            fsp += v * ash[f];
            fdp += v * ash[64 + f];
        }
        rs[g * 64 + n] = fsp;
        rd[g * 64 + n] = fdp;
    }
    __syncthreads();
    if (t < 64) {
        const float LOG2E = 1.44269504f;
        float fdv = (rd[t] + rd[64 + t] + rd[128 + t] + rd[192 + t]) * LOG2E;
        fs[(size_t)h * NN + n0 + t] = (rs[t] + rs[64 + t] + rs[128 + t] + rs[192 + t]) * LOG2E;
        fd[(size_t)h * NN + n0 + t] = fdv;
        unsigned key = fkey(fdv);
        #pragma unroll
        for (int off = 32; off; off >>= 1) key = max(key, (unsigned)__shfl_xor((int)key, off));
        if (t == 0) atomicMax(mxkey + h, key);
    }
}

// ================= Kernel 3: attention — VERIFIED round-4/6 structure (46.4 us) ============
// grid (NN/64, HH), 512 threads = 8 waves. Wave w: j-half h2 = w>>2 (2048 cols),
// row-group rg = w&3 (16 i-rows). One barrier per 64-j iteration; LDS combine epilogue.
__global__ __launch_bounds__(512) void k_attn(const float* __restrict__ fs,
                                              const float* __restrict__ fd,
                                              const unsigned* __restrict__ mxkey,
                                              const unsigned long long* __restrict__ adjm,
                                              const unsigned short* __restrict__ hpT_hi,
                                              const float* __restrict__ hpsum,
                                              float* __restrict__ outp) {
    __shared__ unsigned short hbh[2][2][64 * SP];   // [dbuf][j-half][f*SP+j] = 36864 B

    int t = threadIdx.x;
    int h = blockIdx.y;
    int i0 = blockIdx.x * 64;
    int lane = t & 63;
    int w = t >> 6;              // 0..7
    int h2 = w >> 2;             // j-half
    int rg = w & 3;              // row-group
    int am = lane & 15, aq = lane >> 4;
    int th = t >> 8;             // staging: which half's tile this thread fills
    int ts = t & 255;
    int sr = ts >> 2, sc = (ts & 3) * 16;

    // per-row constants (scaled domain): arg = max(tv, 0.2*tv + Ci), tv = Ai + fdL_j
    float mfdL = funkey(mxkey[h]);
    float fsv = fs[(size_t)h * NN + i0 + rg * 16 + am];
    float sL = fsv + mfdL;
    float mrL = fmaxf(sL, LRELU_ALPHA * sL);
    float Ai = fsv - mrL;
    float Ci = -0.8f * mrL;

    int rgu = __builtin_amdgcn_readfirstlane(rg);
    int h2u = __builtin_amdgcn_readfirstlane(h2);
    const unsigned long long* mbase = adjm + ((size_t)(blockIdx.x * 4 + rgu) * 64) * 16;
    const unsigned short* gH = hpT_hi + (size_t)h * FF * NN;
    const float* fdh = fd + (size_t)h * NN + (size_t)h2u * JCHUNK;   // wave's half

    f32x4 acc[4] = {};
    f32x4 accl = {};
    bf16x8 ones;
    #pragma unroll
    for (int i = 0; i < 8; i++) ones[i] = (short)0x3f80;   // bf16 1.0

    auto stage_load = [&](int j0, uint4& v0, uint4& v1) {   // j0 relative to half
        const uint4* s = (const uint4*)(gH + (size_t)sr * NN + th * JCHUNK + j0 + sc);
        v0 = s[0]; v1 = s[1];
    };
    auto stage_write = [&](int buf, uint4 v0, uint4 v1) {
        *(uint4*)(&hbh[buf][th][sr * SP + sc]) = v0;
        *(uint4*)(&hbh[buf][th][sr * SP + sc + 8]) = v1;
    };
    auto fd_load = [&](int j0, float4* p) {
        p[0] = *(const float4*)(fdh + j0 + aq * 8);
        p[1] = *(const float4*)(fdh + j0 + aq * 8 + 4);
        p[2] = *(const float4*)(fdh + j0 + 32 + aq * 8);
        p[3] = *(const float4*)(fdh + j0 + 32 + aq * 8 + 4);
    };
    // 8 scores -> one bf16x8 B-fragment; masks are wave-uniform 64-bit lane masks
    auto mkfrag = [&](float4 p0, float4 p1, const unsigned long long* mk, int off) -> bf16x8 {
        unsigned eu[8];
        #pragma unroll
        for (int q = 0; q < 2; q++) {
            float4 pv = q ? p1 : p0;
            #pragma unroll
            for (int bq = 0; bq < 4; bq++) {
                float tv = Ai + f4c(pv, bq);
                float uv = __builtin_fmaf(LRELU_ALPHA, tv, Ci);
                float ev = __builtin_amdgcn_exp2f(fmaxf(tv, uv));
                unsigned r;
                asm("v_cndmask_b32 %0, 0, %1, %2"
                    : "=v"(r) : "v"(ev), "s"(mk[off + q * 4 + bq]));
                eu[q * 4 + bq] = r;
            }
        }
        union { unsigned u[4]; bf16x8 v; } pk;
        pk.u[0] = __builtin_amdgcn_perm(eu[1], eu[0], 0x07060302);
        pk.u[1] = __builtin_amdgcn_perm(eu[3], eu[2], 0x07060302);
        pk.u[2] = __builtin_amdgcn_perm(eu[5], eu[4], 0x07060302);
        pk.u[3] = __builtin_amdgcn_perm(eu[7], eu[6], 0x07060302);
        return pk.v;
    };

    bf16x8 Pc0, Pc1;
    {   // prologue: tile 0 of each half
        uint4 v0, v1; float4 pf[4];
        stage_load(0, v0, v1);
        fd_load(0, pf);
        unsigned long long mk[16];
        #pragma unroll
        for (int k = 0; k < 16; k++) mk[k] = mbase[(size_t)(h2u * 32) * 16 + k];
        Pc0 = mkfrag(pf[0], pf[1], mk, 0);
        Pc1 = mkfrag(pf[2], pf[3], mk, 8);
        stage_write(0, v0, v1);
        __syncthreads();
    }

    for (int j0 = 0; j0 < JCHUNK; j0 += 64) {
        int cur = (j0 >> 6) & 1;
        int jn = (j0 + 64) & (JCHUNK - 1);   // wraps on last iter; produce is harmless then
        uint4 v0, v1; float4 pf[4];
        stage_load(jn, v0, v1);              // issue next-tile loads early (T14)
        fd_load(jn, pf);
        unsigned long long mk[16];
        #pragma unroll
        for (int k = 0; k < 16; k++) mk[k] = mbase[(size_t)(h2u * 32 + (jn >> 6)) * 16 + k];

        // consume current tile of this wave's half: hp A-frags from LDS, P from registers
        #pragma unroll
        for (int k2 = 0; k2 < 2; k2++) {
            int ko = k2 * 32 + aq * 8;
            bf16x8 x0 = *(const bf16x8*)(&hbh[cur][h2][(am)      * SP + ko]);
            bf16x8 x1 = *(const bf16x8*)(&hbh[cur][h2][(am + 16) * SP + ko]);
            bf16x8 x2 = *(const bf16x8*)(&hbh[cur][h2][(am + 32) * SP + ko]);
            bf16x8 x3 = *(const bf16x8*)(&hbh[cur][h2][(am + 48) * SP + ko]);
            bf16x8 P = k2 ? Pc1 : Pc0;
            acc[0] = __builtin_amdgcn_mfma_f32_16x16x32_bf16(x0, P, acc[0], 0, 0, 0);
            acc[1] = __builtin_amdgcn_mfma_f32_16x16x32_bf16(x1, P, acc[1], 0, 0, 0);
            acc[2] = __builtin_amdgcn_mfma_f32_16x16x32_bf16(x2, P, acc[2], 0, 0, 0);
            acc[3] = __builtin_amdgcn_mfma_f32_16x16x32_bf16(x3, P, acc[3], 0, 0, 0);
            accl   = __builtin_amdgcn_mfma_f32_16x16x32_bf16(ones, P, accl, 0, 0, 0);
        }

        stage_write(cur ^ 1, v0, v1);        // write next hp tile (other buffer)
        Pc0 = mkfrag(pf[0], pf[1], mk, 0);
        Pc1 = mkfrag(pf[2], pf[3], mk, 8);
        __syncthreads();
    }

    // Cross-half combine in LDS (reuse staging buffer), then normalize + ELU + store.
    float* cb = (float*)hbh;                 // 4096 + 256 floats = 17.4 KB
    if (h2 == 1) {
        #pragma unroll
        for (int mf = 0; mf < 4; mf++)
            *(f32x4*)&cb[((rg * 4 + mf) * 64 + lane) * 4] = acc[mf];
        cb[4096 + rg * 64 + lane] = accl[0];
    }
    __syncthreads();
    if (h2 == 0) {
        #pragma unroll
        for (int mf = 0; mf < 4; mf++) {
            f32x4 o = *(const f32x4*)&cb[((rg * 4 + mf) * 64 + lane) * 4];
            acc[mf] += o;
        }
        float li = accl[0] + cb[4096 + rg * 64 + lane];
        const float invN = 1.0f / NN;
        float rl = 1.f / li;
        int row = i0 + rg * 16 + am;
        float* orow = outp + (size_t)row * (HH * FF) + h * FF;
        #pragma unroll
        for (int mf = 0; mf < 4; mf++) {
            float4 ov;
            #pragma unroll
            for (int r = 0; r < 4; r++) {
                int f = mf * 16 + aq * 4 + r;
                float v;
                if (li > 0.f) v = acc[mf][r] * rl;
                else          v = hpsum[h * FF + f] * invN;   // all-masked row fallback
                v = v > 0.f ? v : __expf(v) - 1.f;
                f4s(ov, r, v);
            }
            *(float4*)(orow + mf * 16 + aq * 4) = ov;
        }
    }
}

extern "C" void kernel_launch(void* const* d_in, const int* in_sizes, int n_in,
                              void* d_out, int out_size, void* d_ws, size_t ws_size,
                              hipStream_t stream) {
    const float* hmat = (const float*)d_in[0];
    const int*   adj  = (const int*)d_in[1];
    const float* W    = (const float*)d_in[2];
    const float* a    = (const float*)d_in[3];
    float* out = (float*)d_out;

    char* ws = (char*)d_ws;
    unsigned short* hpT_hi = (unsigned short*)(ws);                 // 4 MB
    unsigned long long* adjm = (unsigned long long*)(ws + (4u << 20)); // 2 MB
    unsigned short* wt_hi  = (unsigned short*)(ws + (6u << 20));    // 512 KB
    unsigned short* wt_lo  = (unsigned short*)(ws + (6u << 20) + (512u << 10));
    float* fs    = (float*)(ws + (7u << 20));                       // 128 KB
    float* fd    = (float*)(ws + (7u << 20) + (128u << 10));        // 128 KB
    unsigned* mxkey = (unsigned*)(ws + (7u << 20) + (256u << 10));  // 64 B
    float* hpsum = (float*)(mxkey + 16);                            // 2 KB
    unsigned short* h_hi = (unsigned short*)(ws + (8u << 20));      // 4 MB
    unsigned short* h_lo = (unsigned short*)(ws + (12u << 20));     // 4 MB

    k_prep   <<<dim3(2369),          256, 0, stream>>>(adj, W, hmat, adjm, wt_hi, wt_lo,
                                                       h_hi, h_lo, mxkey, hpsum);
    k_hp_mfma<<<dim3(64, 8),         256, 0, stream>>>(h_hi, h_lo, wt_hi, wt_lo, a,
                                                       hpT_hi, fs, fd, hpsum, mxkey);
    k_attn   <<<dim3(NN / 64, HH),   512, 0, stream>>>(fs, fd, mxkey, adjm,
                                                       hpT_hi, hpsum, out);
}